// Round 5
// baseline (254.213 us; speedup 1.0000x reference)
//
#include <hip/hip_runtime.h>

#define HEADS 8
#define HDIM 32
#define NTOK 1024
#define CDIM 256
#define BATCH 16
#define ATT_SCALE 0.17677669529663687f  // 32^-0.5
#define L2E 1.4426950408889634f

typedef __attribute__((ext_vector_type(8))) short bf16x8;   // 8 bf16, 4 VGPRs
typedef __attribute__((ext_vector_type(4))) float f32x4;    // MFMA C/D

__device__ __forceinline__ unsigned short f2bf(float f) {
    unsigned int u = __float_as_uint(f);
    return (unsigned short)((u + 0x7fffu + ((u >> 16) & 1u)) >> 16);  // RNE
}

// ---------------------------------------------------------------------------
// Prep (fused): z<16 -> x (b,c,n) fp32 -> xt16 (b,n,c) bf16;  z==16 -> weights
// fp32 -> bf16.  Wk pre-scaled by ATT_SCALE*log2(e) so the attention S-MFMA
// output is already in log2 domain (bias folded into C, exp = bare v_exp).
// ---------------------------------------------------------------------------
__global__ __launch_bounds__(256) void prep_kernel(
    const float* __restrict__ x,
    const float* __restrict__ Wq, const float* __restrict__ Wk,
    const float* __restrict__ Wv, const float* __restrict__ Wo,
    unsigned short* __restrict__ w16, unsigned short* __restrict__ xt16)
{
    const int t = threadIdx.x;
    if (blockIdx.z == 16) {
        const int which = blockIdx.y;
        const float* src = (which == 0) ? Wq : ((which == 1) ? Wk : ((which == 2) ? Wv : Wo));
        const float scale = (which == 1) ? (ATT_SCALE * L2E) : 1.0f;
        const int base = (blockIdx.x * 256 + t) * 16;
        #pragma unroll
        for (int i = 0; i < 4; ++i) {
            const int idx = base + i * 4;
            float4 v = *(const float4*)&src[idx];
            union { unsigned short h[4]; uint2 u; } pk;
            pk.h[0] = f2bf(v.x * scale); pk.h[1] = f2bf(v.y * scale);
            pk.h[2] = f2bf(v.z * scale); pk.h[3] = f2bf(v.w * scale);
            *(uint2*)&w16[(size_t)which * 65536 + idx] = pk.u;
        }
        return;
    }
    __shared__ float tile[64][65];
    const int b = blockIdx.z, ct = blockIdx.y * 64, nt = blockIdx.x * 64;
    const float* xb = x + ((size_t)b * CDIM + ct) * NTOK + nt;
    const int cc = t >> 4, n4 = (t & 15) * 4;
    #pragma unroll
    for (int i = 0; i < 4; ++i) {
        float4 v = *(const float4*)&xb[(size_t)(cc + 16 * i) * NTOK + n4];
        tile[cc + 16 * i][n4]     = v.x;
        tile[cc + 16 * i][n4 + 1] = v.y;
        tile[cc + 16 * i][n4 + 2] = v.z;
        tile[cc + 16 * i][n4 + 3] = v.w;
    }
    __syncthreads();
    const int c0 = (t & 15) * 4;
    #pragma unroll
    for (int i = 0; i < 4; ++i) {
        const int nl = (t >> 4) + 16 * i;
        union { unsigned short h[4]; uint2 u; } pk;
        #pragma unroll
        for (int j = 0; j < 4; ++j) pk.h[j] = f2bf(tile[c0 + j][nl]);
        *(uint2*)&xt16[((size_t)b * NTOK + nt + nl) * CDIM + ct + c0] = pk.u;
    }
}

// ---------------------------------------------------------------------------
// Kernel 1: QKV projection, bf16 MFMA, depth-1 register prefetch (the short
// K-loop is otherwise load-latency-bound).  XCD-swizzled flat grid.
// ---------------------------------------------------------------------------
__global__ __launch_bounds__(256) void qkv_kernel(
    const unsigned short* __restrict__ xt16,  // (b,n,c) bf16
    const unsigned short* __restrict__ w16,   // wq|wk|wv|wo
    unsigned short* __restrict__ q16,         // (b,h,n,d)
    unsigned short* __restrict__ k16,         // (b,h,n,d), pre-scaled
    unsigned short* __restrict__ vt16)        // (b,h,d,n)
{
    const int id   = blockIdx.x;
    const int b    = (id & 7) * 2 + ((id >> 3) & 1);
    const int rest = id >> 4;            // 0..191
    const int ot   = rest % 12;
    const int pt   = (rest / 12) * 64;
    const int t = threadIdx.x, wid = t >> 6, lane = t & 63;
    const int g = lane >> 4, ln = lane & 15;
    const unsigned short* xb = xt16 + (size_t)b * NTOK * CDIM;
    f32x4 acc[4];
    #pragma unroll
    for (int i = 0; i < 4; ++i) acc[i] = (f32x4){0.f, 0.f, 0.f, 0.f};

    if (ot < 8) {
        const int o_lin = ot * 64 + wid * 16;
        const unsigned short* wsel;
        unsigned short* dst;
        int orow;
        if (o_lin < 256) { wsel = w16;         dst = q16; orow = o_lin; }
        else             { wsel = w16 + 65536; dst = k16; orow = o_lin - 256; }
        const unsigned short* wp = &wsel[(size_t)(orow + ln) * CDIM + g * 8];
        const unsigned short* xp = &xb[(size_t)(pt + ln) * CDIM + g * 8];
        bf16x8 aw = *(const bf16x8*)wp;
        bf16x8 bx[4];
        #pragma unroll
        for (int t2 = 0; t2 < 4; ++t2) bx[t2] = *(const bf16x8*)&xp[(size_t)t2 * 16 * CDIM];
        for (int kt = 0; kt < CDIM; kt += 32) {
            const int nk = (kt + 32) & (CDIM - 1);
            bf16x8 awn = *(const bf16x8*)&wp[nk];
            bf16x8 bxn[4];
            #pragma unroll
            for (int t2 = 0; t2 < 4; ++t2) bxn[t2] = *(const bf16x8*)&xp[(size_t)t2 * 16 * CDIM + nk];
            #pragma unroll
            for (int t2 = 0; t2 < 4; ++t2)
                acc[t2] = __builtin_amdgcn_mfma_f32_16x16x32_bf16(aw, bx[t2], acc[t2], 0, 0, 0);
            aw = awn;
            #pragma unroll
            for (int t2 = 0; t2 < 4; ++t2) bx[t2] = bxn[t2];
        }
        const int ob = orow + g * 4;
        const int head = ob >> 5, dc0 = ob & 31;
        const size_t base = ((size_t)b * HEADS + head) * NTOK * HDIM + dc0;
        #pragma unroll
        for (int t2 = 0; t2 < 4; ++t2) {
            const int p = pt + t2 * 16 + ln;
            union { unsigned short h[4]; uint2 u; } pk;
            #pragma unroll
            for (int r = 0; r < 4; ++r) pk.h[r] = f2bf(acc[t2][r]);
            *(uint2*)&dst[base + (size_t)p * HDIM] = pk.u;
        }
    } else {
        const int vot = (ot - 8) * 64;
        const int pbase = pt + wid * 16;
        const unsigned short* wv = w16 + 2 * 65536;
        const unsigned short* xp = &xb[(size_t)(pbase + ln) * CDIM + g * 8];
        const unsigned short* wp = &wv[(size_t)(vot + ln) * CDIM + g * 8];
        bf16x8 ax = *(const bf16x8*)xp;
        bf16x8 bw[4];
        #pragma unroll
        for (int t2 = 0; t2 < 4; ++t2) bw[t2] = *(const bf16x8*)&wp[(size_t)t2 * 16 * CDIM];
        for (int kt = 0; kt < CDIM; kt += 32) {
            const int nk = (kt + 32) & (CDIM - 1);
            bf16x8 axn = *(const bf16x8*)&xp[nk];
            bf16x8 bwn[4];
            #pragma unroll
            for (int t2 = 0; t2 < 4; ++t2) bwn[t2] = *(const bf16x8*)&wp[(size_t)t2 * 16 * CDIM + nk];
            #pragma unroll
            for (int t2 = 0; t2 < 4; ++t2)
                acc[t2] = __builtin_amdgcn_mfma_f32_16x16x32_bf16(ax, bw[t2], acc[t2], 0, 0, 0);
            ax = axn;
            #pragma unroll
            for (int t2 = 0; t2 < 4; ++t2) bw[t2] = bwn[t2];
        }
        const int p0 = pbase + g * 4;
        #pragma unroll
        for (int t2 = 0; t2 < 4; ++t2) {
            const int o = vot + t2 * 16 + ln;
            const int head = o >> 5, dc = o & 31;
            union { unsigned short h[4]; uint2 u; } pk;
            #pragma unroll
            for (int r = 0; r < 4; ++r) pk.h[r] = f2bf(acc[t2][r]);
            *(uint2*)&vt16[(((size_t)b * HEADS + head) * HDIM + dc) * NTOK + p0] = pk.u;
        }
    }
}

// ---------------------------------------------------------------------------
// Kernel 2: MFMA flash attention.
//  - S^T trick (A=K-perm, B=Q): exp'd P lands directly in PV A-operand layout.
//  - bias folded into S-MFMA C operand via 4 shift-aligned LDS copies of
//    bias*log2e -> one aligned ds_read_b128 per S tile; exp = bare v_exp_f32
//    (K pre-scaled by ATT_SCALE*log2e).
//  - 64-key iterations: two independent 32-key chunks (2x ILP), depth-1
//    register prefetch of next iteration's 8 K/V fragments.
//  - row-sums via MFMA against all-ones B (row-aligned with o0/o1).
//  - XCD swizzle: all 16 q-tiles of a (b,h) on one XCD (K/V L2-resident).
// ---------------------------------------------------------------------------
__global__ __launch_bounds__(256) void attn_kernel(
    const unsigned short* __restrict__ q16,   // (b,h,n,d)
    const unsigned short* __restrict__ k16,   // (b,h,n,d), pre-scaled
    const unsigned short* __restrict__ vt16,  // (b,h,d,n)
    const float* __restrict__ rel_bias,       // (h, 3969)
    unsigned short* __restrict__ ao16)        // (b, n, 256)
{
    __shared__ __align__(16) float bias4[4][2080];  // bias4[a][i] = bias[i+a]*L2E
    __shared__ unsigned short otr[64][36];

    const int id  = blockIdx.x;               // 0..2047
    const int xcd = id & 7;
    const int sub = id >> 3;                  // 0..255
    const int bh_i = xcd * 16 + (sub & 15);   // 16 bh per XCD
    const int qt   = sub >> 4;                // 0..15
    const int b = bh_i >> 3, h = bh_i & 7;

    const int t = threadIdx.x, wid = t >> 6, lane = t & 63;
    const int g = lane >> 4, ln = lane & 15;
    const int qtile = qt * 64, qbase = qtile + wid * 16;
    const size_t bh = (size_t)b * HEADS + h;

    {
        const float* brow = &rel_bias[(size_t)h * 3969];
        for (int i = t; i < 2080; i += 256) {
            #pragma unroll
            for (int a2 = 0; a2 < 4; ++a2)
                bias4[a2][i] = brow[i + a2] * L2E;
        }
    }
    __syncthreads();

    const bf16x8 aq = *(const bf16x8*)&q16[(bh * NTOK + qbase + ln) * HDIM + g * 8];
    const int jrow = 8 * (ln >> 2) + (ln & 3);      // permuted K-row (tile 0)
    const unsigned short* kp  = &k16[bh * NTOK * HDIM + (size_t)jrow * HDIM + g * 8];
    const unsigned short* vp0 = &vt16[(bh * HDIM + ln) * NTOK + g * 8];
    const unsigned short* vp1 = &vt16[(bh * HDIM + 16 + ln) * NTOK + g * 8];
    const int boff = 1056 + 8 * g - qbase - ln;     // bias idx = kb + boff + r (+4 T1)
    const int ba = boff & 3;                        // shift copy (loop-invariant)
    const int bj = boff - ba;                       // 16B-aligned base index

    f32x4 o0 = {0.f, 0.f, 0.f, 0.f}, o1 = {0.f, 0.f, 0.f, 0.f};
    f32x4 lsa = {0.f, 0.f, 0.f, 0.f};
    const short one_bf = (short)0x3F80;
    const bf16x8 ones = {one_bf, one_bf, one_bf, one_bf, one_bf, one_bf, one_bf, one_bf};

    bf16x8 kA0 = *(const bf16x8*)&kp[0];
    bf16x8 kA1 = *(const bf16x8*)&kp[4 * HDIM];
    bf16x8 kB0 = *(const bf16x8*)&kp[32 * HDIM];
    bf16x8 kB1 = *(const bf16x8*)&kp[36 * HDIM];
    bf16x8 vA0 = *(const bf16x8*)&vp0[0];
    bf16x8 vA1 = *(const bf16x8*)&vp1[0];
    bf16x8 vB0 = *(const bf16x8*)&vp0[32];
    bf16x8 vB1 = *(const bf16x8*)&vp1[32];

    for (int kb = 0; kb < NTOK; kb += 64) {
        const int nkb = (kb + 64) & (NTOK - 1);     // wraps: reload iter-0 (harmless)
        bf16x8 kA0n = *(const bf16x8*)&kp[(size_t)nkb * HDIM];
        bf16x8 kA1n = *(const bf16x8*)&kp[(size_t)(nkb + 4) * HDIM];
        bf16x8 kB0n = *(const bf16x8*)&kp[(size_t)(nkb + 32) * HDIM];
        bf16x8 kB1n = *(const bf16x8*)&kp[(size_t)(nkb + 36) * HDIM];
        bf16x8 vA0n = *(const bf16x8*)&vp0[nkb];
        bf16x8 vA1n = *(const bf16x8*)&vp1[nkb];
        bf16x8 vB0n = *(const bf16x8*)&vp0[nkb + 32];
        bf16x8 vB1n = *(const bf16x8*)&vp1[nkb + 32];

        // C-init = bias (log2 domain), aligned b128 reads from shifted copies
        f32x4 cA0 = *(const f32x4*)&bias4[ba][kb + bj];
        f32x4 cA1 = *(const f32x4*)&bias4[ba][kb + bj + 4];
        f32x4 cB0 = *(const f32x4*)&bias4[ba][kb + bj + 32];
        f32x4 cB1 = *(const f32x4*)&bias4[ba][kb + bj + 36];

        f32x4 sA0 = __builtin_amdgcn_mfma_f32_16x16x32_bf16(kA0, aq, cA0, 0, 0, 0);
        f32x4 sA1 = __builtin_amdgcn_mfma_f32_16x16x32_bf16(kA1, aq, cA1, 0, 0, 0);
        f32x4 sB0 = __builtin_amdgcn_mfma_f32_16x16x32_bf16(kB0, aq, cB0, 0, 0, 0);
        f32x4 sB1 = __builtin_amdgcn_mfma_f32_16x16x32_bf16(kB1, aq, cB1, 0, 0, 0);

        // chunk A: exp2 + round-half-up pack -> PV A-frag
        union { int i4[4]; bf16x8 v; } apA, apB;
        float eA[8], eB[8];
        #pragma unroll
        for (int r = 0; r < 4; ++r) {
            eA[r]     = __builtin_amdgcn_exp2f(sA0[r]);
            eA[4 + r] = __builtin_amdgcn_exp2f(sA1[r]);
        }
        #pragma unroll
        for (int p2 = 0; p2 < 4; ++p2) {
            unsigned u0 = __float_as_uint(eA[p2 * 2])     + 0x8000u;
            unsigned u1 = __float_as_uint(eA[p2 * 2 + 1]) + 0x8000u;
            apA.i4[p2] = (int)((u1 & 0xffff0000u) | (u0 >> 16));
        }
        o0  = __builtin_amdgcn_mfma_f32_16x16x32_bf16(apA.v, vA0, o0, 0, 0, 0);
        o1  = __builtin_amdgcn_mfma_f32_16x16x32_bf16(apA.v, vA1, o1, 0, 0, 0);
        lsa = __builtin_amdgcn_mfma_f32_16x16x32_bf16(apA.v, ones, lsa, 0, 0, 0);

        #pragma unroll
        for (int r = 0; r < 4; ++r) {
            eB[r]     = __builtin_amdgcn_exp2f(sB0[r]);
            eB[4 + r] = __builtin_amdgcn_exp2f(sB1[r]);
        }
        #pragma unroll
        for (int p2 = 0; p2 < 4; ++p2) {
            unsigned u0 = __float_as_uint(eB[p2 * 2])     + 0x8000u;
            unsigned u1 = __float_as_uint(eB[p2 * 2 + 1]) + 0x8000u;
            apB.i4[p2] = (int)((u1 & 0xffff0000u) | (u0 >> 16));
        }
        o0  = __builtin_amdgcn_mfma_f32_16x16x32_bf16(apB.v, vB0, o0, 0, 0, 0);
        o1  = __builtin_amdgcn_mfma_f32_16x16x32_bf16(apB.v, vB1, o1, 0, 0, 0);
        lsa = __builtin_amdgcn_mfma_f32_16x16x32_bf16(apB.v, ones, lsa, 0, 0, 0);

        kA0 = kA0n; kA1 = kA1n; kB0 = kB0n; kB1 = kB1n;
        vA0 = vA0n; vA1 = vA1n; vB0 = vB0n; vB1 = vB1n;
    }

    // lsa[r] = full row-sum for query qbase+g*4+r — row-aligned with o0/o1
    #pragma unroll
    for (int r = 0; r < 4; ++r) {
        float inv = 1.f / lsa[r];
        o0[r] *= inv;
        o1[r] *= inv;
    }

    // intra-wave LDS transpose (rows owned by this wave; no barrier)
    #pragma unroll
    for (int r = 0; r < 4; ++r) {
        otr[wid * 16 + g * 4 + r][ln]      = f2bf(o0[r]);
        otr[wid * 16 + g * 4 + r][ln + 16] = f2bf(o1[r]);
    }
    const int row = wid * 16 + (lane >> 2);
    const int ch  = (lane & 3) * 8;
    uint2 lo = *(uint2*)&otr[row][ch];
    uint2 hi = *(uint2*)&otr[row][ch + 4];
    uint4 st; st.x = lo.x; st.y = lo.y; st.z = hi.x; st.w = hi.y;
    *(uint4*)&ao16[((size_t)b * NTOK + qtile + row) * CDIM + h * HDIM + ch] = st;
}

// ---------------------------------------------------------------------------
// Kernel 3: output projection, bf16 MFMA, depth-1 prefetch, XCD-swizzled.
// ---------------------------------------------------------------------------
__global__ __launch_bounds__(256) void outproj_kernel(
    const unsigned short* __restrict__ ao16,  // (b,n,256)
    const unsigned short* __restrict__ wo16,  // (256,256)
    const float* __restrict__ bo,
    float* __restrict__ y)                    // (b,256,n)
{
    const int id   = blockIdx.x;
    const int b    = (id & 7) * 2 + ((id >> 3) & 1);
    const int rest = id >> 4;                 // 0..63
    const int ct   = (rest & 3) * 64;
    const int pt   = (rest >> 2) * 64;
    const int t = threadIdx.x, wid = t >> 6, lane = t & 63;
    const int g = lane >> 4, ln = lane & 15;
    const int cbase = ct + wid * 16;
    const unsigned short* ab = ao16 + (size_t)b * NTOK * CDIM;
    const unsigned short* wp = &wo16[(size_t)(cbase + ln) * CDIM + g * 8];
    const unsigned short* xp = &ab[(size_t)(pt + ln) * CDIM + g * 8];
    f32x4 acc[4];
    #pragma unroll
    for (int i = 0; i < 4; ++i) acc[i] = (f32x4){0.f, 0.f, 0.f, 0.f};

    bf16x8 aw = *(const bf16x8*)wp;
    bf16x8 bx[4];
    #pragma unroll
    for (int t2 = 0; t2 < 4; ++t2) bx[t2] = *(const bf16x8*)&xp[(size_t)t2 * 16 * CDIM];
    for (int kt = 0; kt < CDIM; kt += 32) {
        const int nk = (kt + 32) & (CDIM - 1);
        bf16x8 awn = *(const bf16x8*)&wp[nk];
        bf16x8 bxn[4];
        #pragma unroll
        for (int t2 = 0; t2 < 4; ++t2) bxn[t2] = *(const bf16x8*)&xp[(size_t)t2 * 16 * CDIM + nk];
        #pragma unroll
        for (int t2 = 0; t2 < 4; ++t2)
            acc[t2] = __builtin_amdgcn_mfma_f32_16x16x32_bf16(aw, bx[t2], acc[t2], 0, 0, 0);
        aw = awn;
        #pragma unroll
        for (int t2 = 0; t2 < 4; ++t2) bx[t2] = bxn[t2];
    }
    #pragma unroll
    for (int r = 0; r < 4; ++r) {
        const int c = cbase + g * 4 + r;
        const float bias = bo[c];
        #pragma unroll
        for (int t2 = 0; t2 < 4; ++t2)
            y[((size_t)b * CDIM + c) * NTOK + pt + t2 * 16 + ln] = acc[t2][r] + bias;
    }
}

// ---------------------------------------------------------------------------
extern "C" void kernel_launch(void* const* d_in, const int* in_sizes, int n_in,
                              void* d_out, int out_size, void* d_ws, size_t ws_size,
                              hipStream_t stream) {
    const float* x        = (const float*)d_in[0];
    const float* Wq       = (const float*)d_in[1];
    const float* Wk       = (const float*)d_in[2];
    const float* Wv       = (const float*)d_in[3];
    const float* Wo       = (const float*)d_in[4];
    const float* bo       = (const float*)d_in[5];
    const float* rel_bias = (const float*)d_in[6];
    (void)in_sizes; (void)n_in; (void)ws_size; (void)out_size;
    // d_in[7] = rel_idx: unused — bias index computed analytically (j - p + 1056)

    unsigned short* ws16 = (unsigned short*)d_ws;
    unsigned short* q16  = ws16;                              // 8 MB
    unsigned short* k16  = ws16 + (size_t)4 * 1024 * 1024;    // 8 MB
    unsigned short* vt16 = ws16 + (size_t)8 * 1024 * 1024;    // 8 MB
    unsigned short* xt16 = ws16 + (size_t)12 * 1024 * 1024;   // 8 MB
    unsigned short* ao16 = ws16 + (size_t)16 * 1024 * 1024;   // 8 MB
    unsigned short* w16  = ws16 + (size_t)20 * 1024 * 1024;   // 512 KB
    float* y = (float*)d_out;

    prep_kernel<<<dim3(16, 4, 17), 256, 0, stream>>>(x, Wq, Wk, Wv, Wo, w16, xt16);
    qkv_kernel<<<3072, 256, 0, stream>>>(xt16, w16, q16, k16, vt16);
    attn_kernel<<<2048, 256, 0, stream>>>(q16, k16, vt16, rel_bias, ao16);
    outproj_kernel<<<1024, 256, 0, stream>>>(ao16, w16 + 3 * 65536, bo, y);
}

// Round 7
// 217.384 us; speedup vs baseline: 1.1694x; 1.1694x over previous
//
#include <hip/hip_runtime.h>

#define HEADS 8
#define HDIM 32
#define NTOK 1024
#define CDIM 256
#define BATCH 16
#define ATT_SCALE 0.17677669529663687f  // 32^-0.5
#define L2E 1.4426950408889634f

typedef __attribute__((ext_vector_type(8))) short bf16x8;   // 8 bf16, 4 VGPRs
typedef __attribute__((ext_vector_type(4))) float f32x4;    // MFMA C/D

__device__ __forceinline__ unsigned short f2bf(float f) {
    unsigned int u = __float_as_uint(f);
    return (unsigned short)((u + 0x7fffu + ((u >> 16) & 1u)) >> 16);  // RNE
}

// ---------------------------------------------------------------------------
// Prep (fused): z<16 -> x (b,c,n) fp32 -> xt16 (b,n,c) bf16;  z==16 -> weights
// fp32 -> bf16.  Wk pre-scaled by ATT_SCALE*log2(e): attention S-MFMA output
// is directly in log2 domain (exp = v_exp_f32 after one bias fma).
// ---------------------------------------------------------------------------
__global__ __launch_bounds__(256) void prep_kernel(
    const float* __restrict__ x,
    const float* __restrict__ Wq, const float* __restrict__ Wk,
    const float* __restrict__ Wv, const float* __restrict__ Wo,
    unsigned short* __restrict__ w16, unsigned short* __restrict__ xt16)
{
    const int t = threadIdx.x;
    if (blockIdx.z == 16) {
        const int which = blockIdx.y;
        const float* src = (which == 0) ? Wq : ((which == 1) ? Wk : ((which == 2) ? Wv : Wo));
        const float scale = (which == 1) ? (ATT_SCALE * L2E) : 1.0f;
        const int base = (blockIdx.x * 256 + t) * 16;
        #pragma unroll
        for (int i = 0; i < 4; ++i) {
            const int idx = base + i * 4;
            float4 v = *(const float4*)&src[idx];
            union { unsigned short h[4]; uint2 u; } pk;
            pk.h[0] = f2bf(v.x * scale); pk.h[1] = f2bf(v.y * scale);
            pk.h[2] = f2bf(v.z * scale); pk.h[3] = f2bf(v.w * scale);
            *(uint2*)&w16[(size_t)which * 65536 + idx] = pk.u;
        }
        return;
    }
    __shared__ float tile[64][65];
    const int b = blockIdx.z, ct = blockIdx.y * 64, nt = blockIdx.x * 64;
    const float* xb = x + ((size_t)b * CDIM + ct) * NTOK + nt;
    const int cc = t >> 4, n4 = (t & 15) * 4;
    #pragma unroll
    for (int i = 0; i < 4; ++i) {
        float4 v = *(const float4*)&xb[(size_t)(cc + 16 * i) * NTOK + n4];
        tile[cc + 16 * i][n4]     = v.x;
        tile[cc + 16 * i][n4 + 1] = v.y;
        tile[cc + 16 * i][n4 + 2] = v.z;
        tile[cc + 16 * i][n4 + 3] = v.w;
    }
    __syncthreads();
    const int c0 = (t & 15) * 4;
    #pragma unroll
    for (int i = 0; i < 4; ++i) {
        const int nl = (t >> 4) + 16 * i;
        union { unsigned short h[4]; uint2 u; } pk;
        #pragma unroll
        for (int j = 0; j < 4; ++j) pk.h[j] = f2bf(tile[c0 + j][nl]);
        *(uint2*)&xt16[((size_t)b * NTOK + nt + nl) * CDIM + ct + c0] = pk.u;
    }
}

// ---------------------------------------------------------------------------
// Kernel 1: QKV projection, bf16 MFMA (round-4 form), XCD-swizzled flat grid.
// ---------------------------------------------------------------------------
__global__ __launch_bounds__(256) void qkv_kernel(
    const unsigned short* __restrict__ xt16,  // (b,n,c) bf16
    const unsigned short* __restrict__ w16,   // wq|wk|wv|wo
    unsigned short* __restrict__ q16,         // (b,h,n,d)
    unsigned short* __restrict__ k16,         // (b,h,n,d), pre-scaled
    unsigned short* __restrict__ vt16)        // (b,h,d,n)
{
    const int id   = blockIdx.x;
    const int b    = (id & 7) * 2 + ((id >> 3) & 1);
    const int rest = id >> 4;            // 0..191
    const int ot   = rest % 12;
    const int pt   = (rest / 12) * 64;
    const int t = threadIdx.x, wid = t >> 6, lane = t & 63;
    const int g = lane >> 4, ln = lane & 15;
    const unsigned short* xb = xt16 + (size_t)b * NTOK * CDIM;
    f32x4 acc[4];
    #pragma unroll
    for (int i = 0; i < 4; ++i) acc[i] = (f32x4){0.f, 0.f, 0.f, 0.f};

    if (ot < 8) {
        const int o_lin = ot * 64 + wid * 16;
        const unsigned short* wsel;
        unsigned short* dst;
        int orow;
        if (o_lin < 256) { wsel = w16;         dst = q16; orow = o_lin; }
        else             { wsel = w16 + 65536; dst = k16; orow = o_lin - 256; }
        for (int kt = 0; kt < CDIM; kt += 32) {
            bf16x8 aw = *(const bf16x8*)&wsel[(size_t)(orow + ln) * CDIM + kt + g * 8];
            #pragma unroll
            for (int t2 = 0; t2 < 4; ++t2) {
                bf16x8 bx = *(const bf16x8*)&xb[(size_t)(pt + t2 * 16 + ln) * CDIM + kt + g * 8];
                acc[t2] = __builtin_amdgcn_mfma_f32_16x16x32_bf16(aw, bx, acc[t2], 0, 0, 0);
            }
        }
        const int ob = orow + g * 4;
        const int head = ob >> 5, dc0 = ob & 31;
        const size_t base = ((size_t)b * HEADS + head) * NTOK * HDIM + dc0;
        #pragma unroll
        for (int t2 = 0; t2 < 4; ++t2) {
            const int p = pt + t2 * 16 + ln;
            union { unsigned short h[4]; uint2 u; } pk;
            #pragma unroll
            for (int r = 0; r < 4; ++r) pk.h[r] = f2bf(acc[t2][r]);
            *(uint2*)&dst[base + (size_t)p * HDIM] = pk.u;
        }
    } else {
        const int vot = (ot - 8) * 64;
        const int pbase = pt + wid * 16;
        const unsigned short* wv = w16 + 2 * 65536;
        for (int kt = 0; kt < CDIM; kt += 32) {
            bf16x8 ax = *(const bf16x8*)&xb[(size_t)(pbase + ln) * CDIM + kt + g * 8];
            #pragma unroll
            for (int t2 = 0; t2 < 4; ++t2) {
                bf16x8 bw = *(const bf16x8*)&wv[(size_t)(vot + t2 * 16 + ln) * CDIM + kt + g * 8];
                acc[t2] = __builtin_amdgcn_mfma_f32_16x16x32_bf16(ax, bw, acc[t2], 0, 0, 0);
            }
        }
        const int p0 = pbase + g * 4;
        #pragma unroll
        for (int t2 = 0; t2 < 4; ++t2) {
            const int o = vot + t2 * 16 + ln;
            const int head = o >> 5, dc = o & 31;
            union { unsigned short h[4]; uint2 u; } pk;
            #pragma unroll
            for (int r = 0; r < 4; ++r) pk.h[r] = f2bf(acc[t2][r]);
            *(uint2*)&vt16[(((size_t)b * HEADS + head) * HDIM + dc) * NTOK + p0] = pk.u;
        }
    }
}

// ---------------------------------------------------------------------------
// Kernel 2: MFMA flash attention, K fully LDS-resident.
//  Block = (b, h, half of queries): 1024 thr / 16 waves, wave owns 32 queries.
//  - K (1024x32 bf16 = 64 KiB) staged once into LDS by linear copy; the
//    S-MFMA critical chain reads K via ds_read_b128 only (no global latency).
//  - V stays global (depth-1 register prefetch; feeds accumulate side only).
//  - bias: raw global fp32 scalar loads (L1-hot 8KB row), folded with v_fma.
//  - S^T trick (A=K-perm, B=Q) -> exp'd P is directly the PV A-operand.
//  - row-sums via MFMA against all-ones B.
//  - XCD swizzle: both query-halves of a (b,h) on one XCD.
//  FIX (R6->R7): epilogue stored only 8 of 16 bf16 per lane -> half of ao16's
//  d-columns stayed poisoned (absmax 1.97e-2). Now two uint4 per lane (32B),
//  covering all 32 d per query row.
// ---------------------------------------------------------------------------
__global__ __launch_bounds__(1024, 4) void attn_kernel(
    const unsigned short* __restrict__ q16,   // (b,h,n,d)
    const unsigned short* __restrict__ k16,   // (b,h,n,d), pre-scaled by ATT_SCALE*L2E
    const unsigned short* __restrict__ vt16,  // (b,h,d,n)
    const float* __restrict__ rel_bias,       // (h, 3969)
    unsigned short* __restrict__ ao16)        // (b, n, 256)
{
    __shared__ union {
        unsigned short k[NTOK * HDIM];        // 64 KiB, rows = keys (natural order)
        unsigned short otr[16][32][40];       // per-wave O transpose (after barrier)
    } sm;

    const int id   = blockIdx.x;              // 0..255
    const int bh_i = (id & 7) * 16 + (id >> 4);     // XCD x owns bh [16x,16x+16)
    const int half = (id >> 3) & 1;
    const int b = bh_i >> 3, h = bh_i & 7;
    const size_t bh = (size_t)b * HEADS + h;

    const int t = threadIdx.x, wid = t >> 6, lane = t & 63;
    const int g = lane >> 4, ln = lane & 15;
    const int qb = half * 512 + wid * 32;     // wave's 32 queries

    // ---- stage K into LDS (linear 64KB copy, fully coalesced) ----
    {
        const uint4* kg = (const uint4*)&k16[bh * NTOK * HDIM];
        uint4* kl = (uint4*)sm.k;
        #pragma unroll
        for (int p = 0; p < 4; ++p) kl[p * 1024 + t] = kg[p * 1024 + t];
    }

    const bf16x8 aq0 = *(const bf16x8*)&q16[(bh * NTOK + qb + ln) * HDIM + g * 8];
    const bf16x8 aq1 = *(const bf16x8*)&q16[(bh * NTOK + qb + 16 + ln) * HDIM + g * 8];
    const int jrow = 8 * (ln >> 2) + (ln & 3);      // permuted K-row (tile 0)
    const unsigned short* vp0 = &vt16[(bh * HDIM + ln) * NTOK + g * 8];
    const unsigned short* vp1 = &vt16[(bh * HDIM + 16 + ln) * NTOK + g * 8];
    const float* brow = &rel_bias[(size_t)h * 3969];
    const int boff0 = 1056 + 8 * g - qb - ln;       // qfrag 0: idx = kb+boff0+i
    const int boff1 = boff0 - 16;                   // qfrag 1

    f32x4 o00 = {0.f,0.f,0.f,0.f}, o01 = {0.f,0.f,0.f,0.f};
    f32x4 o10 = {0.f,0.f,0.f,0.f}, o11 = {0.f,0.f,0.f,0.f};
    f32x4 ls0 = {0.f,0.f,0.f,0.f}, ls1 = {0.f,0.f,0.f,0.f};
    const short one_bf = (short)0x3F80;
    const bf16x8 ones = {one_bf,one_bf,one_bf,one_bf,one_bf,one_bf,one_bf,one_bf};

    __syncthreads();                                 // K staged

    bf16x8 vA0 = *(const bf16x8*)&vp0[0];
    bf16x8 vA1 = *(const bf16x8*)&vp1[0];

    for (int kb = 0; kb < NTOK; kb += 32) {
        const int nkb = (kb + 32) & (NTOK - 1);
        bf16x8 vA0n = *(const bf16x8*)&vp0[nkb];     // depth-1 V prefetch
        bf16x8 vA1n = *(const bf16x8*)&vp1[nkb];

        // bias for this chunk (L1-hot)
        float bc0[8], bc1[8];
        #pragma unroll
        for (int i = 0; i < 8; ++i) bc0[i] = brow[kb + boff0 + i];
        #pragma unroll
        for (int i = 0; i < 8; ++i) bc1[i] = brow[kb + boff1 + i];

        // K fragments from LDS (permuted rows)
        const bf16x8 kf0 = *(const bf16x8*)&sm.k[(kb + jrow) * HDIM + g * 8];
        const bf16x8 kf1 = *(const bf16x8*)&sm.k[(kb + jrow + 4) * HDIM + g * 8];

        f32x4 s00 = __builtin_amdgcn_mfma_f32_16x16x32_bf16(kf0, aq0, (f32x4){0.f,0.f,0.f,0.f}, 0, 0, 0);
        f32x4 s01 = __builtin_amdgcn_mfma_f32_16x16x32_bf16(kf1, aq0, (f32x4){0.f,0.f,0.f,0.f}, 0, 0, 0);
        f32x4 s10 = __builtin_amdgcn_mfma_f32_16x16x32_bf16(kf0, aq1, (f32x4){0.f,0.f,0.f,0.f}, 0, 0, 0);
        f32x4 s11 = __builtin_amdgcn_mfma_f32_16x16x32_bf16(kf1, aq1, (f32x4){0.f,0.f,0.f,0.f}, 0, 0, 0);

        // exp2(s + bias*L2E), round-half-up pack -> PV A-frags
        union { int i4[4]; bf16x8 v; } ap0, ap1;
        #pragma unroll
        for (int r = 0; r < 4; ++r) {
            float e0 = __builtin_amdgcn_exp2f(fmaf(bc0[r],     L2E, s00[r]));
            float e1 = __builtin_amdgcn_exp2f(fmaf(bc0[4 + r], L2E, s01[r]));
            unsigned u0 = __float_as_uint(e0) + 0x8000u;
            unsigned u1 = __float_as_uint(e1) + 0x8000u;
            ((unsigned short*)ap0.i4)[r]     = (unsigned short)(u0 >> 16);
            ((unsigned short*)ap0.i4)[4 + r] = (unsigned short)(u1 >> 16);
        }
        #pragma unroll
        for (int r = 0; r < 4; ++r) {
            float e0 = __builtin_amdgcn_exp2f(fmaf(bc1[r],     L2E, s10[r]));
            float e1 = __builtin_amdgcn_exp2f(fmaf(bc1[4 + r], L2E, s11[r]));
            unsigned u0 = __float_as_uint(e0) + 0x8000u;
            unsigned u1 = __float_as_uint(e1) + 0x8000u;
            ((unsigned short*)ap1.i4)[r]     = (unsigned short)(u0 >> 16);
            ((unsigned short*)ap1.i4)[4 + r] = (unsigned short)(u1 >> 16);
        }

        o00 = __builtin_amdgcn_mfma_f32_16x16x32_bf16(ap0.v, vA0, o00, 0, 0, 0);
        o01 = __builtin_amdgcn_mfma_f32_16x16x32_bf16(ap0.v, vA1, o01, 0, 0, 0);
        ls0 = __builtin_amdgcn_mfma_f32_16x16x32_bf16(ap0.v, ones, ls0, 0, 0, 0);
        o10 = __builtin_amdgcn_mfma_f32_16x16x32_bf16(ap1.v, vA0, o10, 0, 0, 0);
        o11 = __builtin_amdgcn_mfma_f32_16x16x32_bf16(ap1.v, vA1, o11, 0, 0, 0);
        ls1 = __builtin_amdgcn_mfma_f32_16x16x32_bf16(ap1.v, ones, ls1, 0, 0, 0);

        vA0 = vA0n; vA1 = vA1n;
    }

    #pragma unroll
    for (int r = 0; r < 4; ++r) {
        float i0 = 1.f / ls0[r], i1 = 1.f / ls1[r];
        o00[r] *= i0; o01[r] *= i0;
        o10[r] *= i1; o11[r] *= i1;
    }

    __syncthreads();   // all waves done reading K; reuse LDS as otr
    #pragma unroll
    for (int r = 0; r < 4; ++r) {
        sm.otr[wid][g * 4 + r][ln]           = f2bf(o00[r]);
        sm.otr[wid][g * 4 + r][16 + ln]      = f2bf(o01[r]);
        sm.otr[wid][16 + g * 4 + r][ln]      = f2bf(o10[r]);
        sm.otr[wid][16 + g * 4 + r][16 + ln] = f2bf(o11[r]);
    }
    // intra-wave region: same-wave DS ordering, no extra barrier needed.
    // Each lane stores 16 bf16 (two uint4, 32 contiguous bytes): 2 lanes/row
    // x 16 d = all 32 d-columns covered (the R6 bug stored only 8/lane).
    const int row = lane >> 1;                 // 0..31 (q_local)
    const int ch  = (lane & 1) * 16;           // d half: 0 or 16
    uint4 st0 = *(uint4*)&sm.otr[wid][row][ch];
    uint4 st1 = *(uint4*)&sm.otr[wid][row][ch + 8];
    unsigned short* dst = &ao16[((size_t)b * NTOK + qb + row) * CDIM + h * HDIM + ch];
    *(uint4*)dst      = st0;
    *(uint4*)&dst[8]  = st1;
}

// ---------------------------------------------------------------------------
// Kernel 3: output projection, bf16 MFMA (round-4 form), XCD-swizzled.
// ---------------------------------------------------------------------------
__global__ __launch_bounds__(256) void outproj_kernel(
    const unsigned short* __restrict__ ao16,  // (b,n,256)
    const unsigned short* __restrict__ wo16,  // (256,256)
    const float* __restrict__ bo,
    float* __restrict__ y)                    // (b,256,n)
{
    const int id   = blockIdx.x;
    const int b    = (id & 7) * 2 + ((id >> 3) & 1);
    const int rest = id >> 4;                 // 0..63
    const int ct   = (rest & 3) * 64;
    const int pt   = (rest >> 2) * 64;
    const int t = threadIdx.x, wid = t >> 6, lane = t & 63;
    const int g = lane >> 4, ln = lane & 15;
    const int cbase = ct + wid * 16;
    const unsigned short* ab = ao16 + (size_t)b * NTOK * CDIM;
    f32x4 acc[4];
    #pragma unroll
    for (int i = 0; i < 4; ++i) acc[i] = (f32x4){0.f, 0.f, 0.f, 0.f};

    for (int kt = 0; kt < CDIM; kt += 32) {
        bf16x8 aw = *(const bf16x8*)&wo16[(size_t)(cbase + ln) * CDIM + kt + g * 8];
        #pragma unroll
        for (int t2 = 0; t2 < 4; ++t2) {
            bf16x8 bx = *(const bf16x8*)&ab[(size_t)(pt + t2 * 16 + ln) * CDIM + kt + g * 8];
            acc[t2] = __builtin_amdgcn_mfma_f32_16x16x32_bf16(aw, bx, acc[t2], 0, 0, 0);
        }
    }
    #pragma unroll
    for (int r = 0; r < 4; ++r) {
        const int c = cbase + g * 4 + r;
        const float bias = bo[c];
        #pragma unroll
        for (int t2 = 0; t2 < 4; ++t2)
            y[((size_t)b * CDIM + c) * NTOK + pt + t2 * 16 + ln] = acc[t2][r] + bias;
    }
}

// ---------------------------------------------------------------------------
extern "C" void kernel_launch(void* const* d_in, const int* in_sizes, int n_in,
                              void* d_out, int out_size, void* d_ws, size_t ws_size,
                              hipStream_t stream) {
    const float* x        = (const float*)d_in[0];
    const float* Wq       = (const float*)d_in[1];
    const float* Wk       = (const float*)d_in[2];
    const float* Wv       = (const float*)d_in[3];
    const float* Wo       = (const float*)d_in[4];
    const float* bo       = (const float*)d_in[5];
    const float* rel_bias = (const float*)d_in[6];
    (void)in_sizes; (void)n_in; (void)ws_size; (void)out_size;
    // d_in[7] = rel_idx: unused — bias index computed analytically (j - p + 1056)

    unsigned short* ws16 = (unsigned short*)d_ws;
    unsigned short* q16  = ws16;                              // 8 MB
    unsigned short* k16  = ws16 + (size_t)4 * 1024 * 1024;    // 8 MB
    unsigned short* vt16 = ws16 + (size_t)8 * 1024 * 1024;    // 8 MB
    unsigned short* xt16 = ws16 + (size_t)12 * 1024 * 1024;   // 8 MB
    unsigned short* ao16 = ws16 + (size_t)16 * 1024 * 1024;   // 8 MB
    unsigned short* w16  = ws16 + (size_t)20 * 1024 * 1024;   // 512 KB
    float* y = (float*)d_out;

    prep_kernel<<<dim3(16, 4, 17), 256, 0, stream>>>(x, Wq, Wk, Wv, Wo, w16, xt16);
    qkv_kernel<<<3072, 256, 0, stream>>>(xt16, w16, q16, k16, vt16);
    attn_kernel<<<256, 1024, 0, stream>>>(q16, k16, vt16, rel_bias, ao16);
    outproj_kernel<<<1024, 256, 0, stream>>>(ao16, w16 + 3 * 65536, bo, y);
}

// Round 8
// 189.303 us; speedup vs baseline: 1.3429x; 1.1483x over previous
//
#include <hip/hip_runtime.h>

#define HEADS 8
#define HDIM 32
#define NTOK 1024
#define CDIM 256
#define BATCH 16
#define ATT_SCALE 0.17677669529663687f  // 32^-0.5
#define L2E 1.4426950408889634f
#define VSTR 1032   // v_s row stride (shorts): 2064B = 16B-aligned, 4-bank row shift

typedef __attribute__((ext_vector_type(8))) short bf16x8;   // 8 bf16, 4 VGPRs
typedef __attribute__((ext_vector_type(4))) float f32x4;    // MFMA C/D

__device__ __forceinline__ unsigned short f2bf(float f) {
    unsigned int u = __float_as_uint(f);
    return (unsigned short)((u + 0x7fffu + ((u >> 16) & 1u)) >> 16);  // RNE
}

// ---------------------------------------------------------------------------
// Prep (fused): z<16 -> x (b,c,n) fp32 -> xt16 (b,n,c) bf16;  z==16 -> weights
// fp32 -> bf16.  Wk pre-scaled by ATT_SCALE*log2(e): S-MFMA output lands in
// log2 domain (exp = v_exp_f32 after adding bias*log2e).
// ---------------------------------------------------------------------------
__global__ __launch_bounds__(256) void prep_kernel(
    const float* __restrict__ x,
    const float* __restrict__ Wq, const float* __restrict__ Wk,
    const float* __restrict__ Wv, const float* __restrict__ Wo,
    unsigned short* __restrict__ w16, unsigned short* __restrict__ xt16)
{
    const int t = threadIdx.x;
    if (blockIdx.z == 16) {
        const int which = blockIdx.y;
        const float* src = (which == 0) ? Wq : ((which == 1) ? Wk : ((which == 2) ? Wv : Wo));
        const float scale = (which == 1) ? (ATT_SCALE * L2E) : 1.0f;
        const int base = (blockIdx.x * 256 + t) * 16;
        #pragma unroll
        for (int i = 0; i < 4; ++i) {
            const int idx = base + i * 4;
            float4 v = *(const float4*)&src[idx];
            union { unsigned short h[4]; uint2 u; } pk;
            pk.h[0] = f2bf(v.x * scale); pk.h[1] = f2bf(v.y * scale);
            pk.h[2] = f2bf(v.z * scale); pk.h[3] = f2bf(v.w * scale);
            *(uint2*)&w16[(size_t)which * 65536 + idx] = pk.u;
        }
        return;
    }
    __shared__ float tile[64][65];
    const int b = blockIdx.z, ct = blockIdx.y * 64, nt = blockIdx.x * 64;
    const float* xb = x + ((size_t)b * CDIM + ct) * NTOK + nt;
    const int cc = t >> 4, n4 = (t & 15) * 4;
    #pragma unroll
    for (int i = 0; i < 4; ++i) {
        float4 v = *(const float4*)&xb[(size_t)(cc + 16 * i) * NTOK + n4];
        tile[cc + 16 * i][n4]     = v.x;
        tile[cc + 16 * i][n4 + 1] = v.y;
        tile[cc + 16 * i][n4 + 2] = v.z;
        tile[cc + 16 * i][n4 + 3] = v.w;
    }
    __syncthreads();
    const int c0 = (t & 15) * 4;
    #pragma unroll
    for (int i = 0; i < 4; ++i) {
        const int nl = (t >> 4) + 16 * i;
        union { unsigned short h[4]; uint2 u; } pk;
        #pragma unroll
        for (int j = 0; j < 4; ++j) pk.h[j] = f2bf(tile[c0 + j][nl]);
        *(uint2*)&xt16[((size_t)b * NTOK + nt + nl) * CDIM + ct + c0] = pk.u;
    }
}

// ---------------------------------------------------------------------------
// Fused QKV + flash attention.  Block = (b, h, query-half): 1024 thr/16 waves.
//  Stage 1 (in-kernel QKV, ~160 MFMA/wave):
//    K (1024x32) -> LDS (n,d);  Q (512 rows) -> LDS (V-region overlay) ->
//    same-wave readback into A-frags;  barrier;  V (32x1024, padded stride)
//    -> LDS.  All inputs from L2-hot xt16/w16.
//  Stage 2 (attention, 32 iters): ZERO global ops in the loop — K/V/bias all
//  LDS, P register-resident via the S^T permutation trick, row-sums via MFMA
//  against all-ones B.  D-layout convention (verified R2-R7): lane(g,ln) holds
//  D[m=g*4+r][n=ln], m = A-row index, n = B-row index.
// ---------------------------------------------------------------------------
__global__ __launch_bounds__(1024, 4) void attn_kernel(
    const unsigned short* __restrict__ xt16,  // (b,n,c) bf16
    const unsigned short* __restrict__ w16,   // wq|wk|wv|wo (wk pre-scaled)
    const float* __restrict__ rel_bias,       // (h, 3969)
    unsigned short* __restrict__ ao16)        // (b, n, 256)
{
    __shared__ __align__(16) unsigned char smem[65536 + VSTR * 32 * 2 + 2080 * 4];
    unsigned short* k_s  = (unsigned short*)smem;                    // (1024, 32)
    unsigned short* v_s  = (unsigned short*)(smem + 65536);          // (32, VSTR)
    unsigned short* q_s  = (unsigned short*)(smem + 65536);          // overlay (512, 32)
    float*          bias_s = (float*)(smem + 65536 + VSTR * 32 * 2); // 2080

    const int id   = blockIdx.x;                    // 0..255
    const int bh_i = (id & 7) * 16 + (id >> 4);     // XCD x owns bh [16x,16x+16)
    const int half = (id >> 3) & 1;
    const int b = bh_i >> 3, h = bh_i & 7;

    const int t = threadIdx.x, wid = t >> 6, lane = t & 63;
    const int g = lane >> 4, ln = lane & 15;
    const int qb = half * 512 + wid * 32;           // wave's 32 queries

    const unsigned short* xb  = xt16 + (size_t)b * NTOK * CDIM;
    const unsigned short* wqh = w16 + (size_t)(h * 32) * CDIM;
    const unsigned short* wkh = w16 + 65536 + (size_t)(h * 32) * CDIM;
    const unsigned short* wvh = w16 + 2 * 65536 + (size_t)(h * 32) * CDIM;

    // bias (pre-scaled by log2e) -> LDS
    {
        const float* brow = rel_bias + (size_t)h * 3969;
        for (int i = t; i < 2080; i += 1024) bias_s[i] = brow[i] * L2E;
    }

    // ---- Stage 1a: K GEMM — tokens [wid*64, wid*64+64) x 32 ch, K=256 ----
    {
        const int tr = wid * 64;
        f32x4 acc[4][2];
        #pragma unroll
        for (int m = 0; m < 4; ++m)
            #pragma unroll
            for (int n = 0; n < 2; ++n) acc[m][n] = (f32x4){0.f, 0.f, 0.f, 0.f};
        for (int kt = 0; kt < CDIM; kt += 32) {
            bf16x8 a[4], w2[2];
            #pragma unroll
            for (int m = 0; m < 4; ++m)
                a[m] = *(const bf16x8*)&xb[(size_t)(tr + m * 16 + ln) * CDIM + kt + g * 8];
            #pragma unroll
            for (int n = 0; n < 2; ++n)
                w2[n] = *(const bf16x8*)&wkh[(size_t)(n * 16 + ln) * CDIM + kt + g * 8];
            #pragma unroll
            for (int m = 0; m < 4; ++m)
                #pragma unroll
                for (int n = 0; n < 2; ++n)
                    acc[m][n] = __builtin_amdgcn_mfma_f32_16x16x32_bf16(a[m], w2[n], acc[m][n], 0, 0, 0);
        }
        #pragma unroll
        for (int m = 0; m < 4; ++m)
            #pragma unroll
            for (int n = 0; n < 2; ++n)
                #pragma unroll
                for (int r = 0; r < 4; ++r)
                    k_s[(size_t)(tr + m * 16 + g * 4 + r) * HDIM + n * 16 + ln] = f2bf(acc[m][n][r]);
    }

    // ---- Stage 1b: Q GEMM — rows [qb, qb+32); write+read via q_s (same wave) ----
    bf16x8 aq0, aq1;
    {
        f32x4 acc[2][2];
        #pragma unroll
        for (int m = 0; m < 2; ++m)
            #pragma unroll
            for (int n = 0; n < 2; ++n) acc[m][n] = (f32x4){0.f, 0.f, 0.f, 0.f};
        for (int kt = 0; kt < CDIM; kt += 32) {
            bf16x8 a[2], w2[2];
            #pragma unroll
            for (int m = 0; m < 2; ++m)
                a[m] = *(const bf16x8*)&xb[(size_t)(qb + m * 16 + ln) * CDIM + kt + g * 8];
            #pragma unroll
            for (int n = 0; n < 2; ++n)
                w2[n] = *(const bf16x8*)&wqh[(size_t)(n * 16 + ln) * CDIM + kt + g * 8];
            #pragma unroll
            for (int m = 0; m < 2; ++m)
                #pragma unroll
                for (int n = 0; n < 2; ++n)
                    acc[m][n] = __builtin_amdgcn_mfma_f32_16x16x32_bf16(a[m], w2[n], acc[m][n], 0, 0, 0);
        }
        const int lr = wid * 32;   // local row base in q_s
        #pragma unroll
        for (int m = 0; m < 2; ++m)
            #pragma unroll
            for (int n = 0; n < 2; ++n)
                #pragma unroll
                for (int r = 0; r < 4; ++r)
                    q_s[(size_t)(lr + m * 16 + g * 4 + r) * HDIM + n * 16 + ln] = f2bf(acc[m][n][r]);
        // same-wave DS in-order: A-frag readback without barrier
        aq0 = *(const bf16x8*)&q_s[(size_t)(lr + ln) * HDIM + g * 8];
        aq1 = *(const bf16x8*)&q_s[(size_t)(lr + 16 + ln) * HDIM + g * 8];
    }

    __syncthreads();   // all waves done reading q_s; K fully written

    // ---- Stage 1c: V GEMM — 32 ch x tokens [wid*64, +64), into padded v_s ----
    {
        const int tb = wid * 64;
        f32x4 acc[2][4];
        #pragma unroll
        for (int m = 0; m < 2; ++m)
            #pragma unroll
            for (int n = 0; n < 4; ++n) acc[m][n] = (f32x4){0.f, 0.f, 0.f, 0.f};
        for (int kt = 0; kt < CDIM; kt += 32) {
            bf16x8 aw[2], bx[4];
            #pragma unroll
            for (int m = 0; m < 2; ++m)
                aw[m] = *(const bf16x8*)&wvh[(size_t)(m * 16 + ln) * CDIM + kt + g * 8];
            #pragma unroll
            for (int n = 0; n < 4; ++n)
                bx[n] = *(const bf16x8*)&xb[(size_t)(tb + n * 16 + ln) * CDIM + kt + g * 8];
            #pragma unroll
            for (int m = 0; m < 2; ++m)
                #pragma unroll
                for (int n = 0; n < 4; ++n)
                    acc[m][n] = __builtin_amdgcn_mfma_f32_16x16x32_bf16(aw[m], bx[n], acc[m][n], 0, 0, 0);
        }
        #pragma unroll
        for (int m = 0; m < 2; ++m)
            #pragma unroll
            for (int n = 0; n < 4; ++n)
                #pragma unroll
                for (int r = 0; r < 4; ++r)
                    v_s[(size_t)(m * 16 + g * 4 + r) * VSTR + tb + n * 16 + ln] = f2bf(acc[m][n][r]);
    }

    __syncthreads();   // K and V both LDS-resident

    // ---- Stage 2: attention main loop (no global, no barriers) ----
    const int jrow  = 8 * (ln >> 2) + (ln & 3);      // permuted K-row (tile 0)
    const int boff0 = 1056 + 8 * g - qb - ln;        // qfrag0 bias base
    const int boff1 = boff0 - 16;                    // qfrag1

    f32x4 o00 = {0.f,0.f,0.f,0.f}, o01 = {0.f,0.f,0.f,0.f};
    f32x4 o10 = {0.f,0.f,0.f,0.f}, o11 = {0.f,0.f,0.f,0.f};
    f32x4 ls0 = {0.f,0.f,0.f,0.f}, ls1 = {0.f,0.f,0.f,0.f};
    const short one_bf = (short)0x3F80;
    const bf16x8 ones = {one_bf,one_bf,one_bf,one_bf,one_bf,one_bf,one_bf,one_bf};

    for (int kb = 0; kb < NTOK; kb += 32) {
        const bf16x8 kf0 = *(const bf16x8*)&k_s[(size_t)(kb + jrow) * HDIM + g * 8];
        const bf16x8 kf1 = *(const bf16x8*)&k_s[(size_t)(kb + jrow + 4) * HDIM + g * 8];
        const bf16x8 vA0 = *(const bf16x8*)&v_s[(size_t)ln * VSTR + kb + g * 8];
        const bf16x8 vA1 = *(const bf16x8*)&v_s[(size_t)(16 + ln) * VSTR + kb + g * 8];
        float bc0[8], bc1[8];
        #pragma unroll
        for (int i = 0; i < 8; ++i) bc0[i] = bias_s[kb + boff0 + i];
        #pragma unroll
        for (int i = 0; i < 8; ++i) bc1[i] = bias_s[kb + boff1 + i];

        f32x4 s00 = __builtin_amdgcn_mfma_f32_16x16x32_bf16(kf0, aq0, (f32x4){0.f,0.f,0.f,0.f}, 0, 0, 0);
        f32x4 s01 = __builtin_amdgcn_mfma_f32_16x16x32_bf16(kf1, aq0, (f32x4){0.f,0.f,0.f,0.f}, 0, 0, 0);
        f32x4 s10 = __builtin_amdgcn_mfma_f32_16x16x32_bf16(kf0, aq1, (f32x4){0.f,0.f,0.f,0.f}, 0, 0, 0);
        f32x4 s11 = __builtin_amdgcn_mfma_f32_16x16x32_bf16(kf1, aq1, (f32x4){0.f,0.f,0.f,0.f}, 0, 0, 0);

        union { int i4[4]; bf16x8 v; } ap0, ap1;
        #pragma unroll
        for (int r = 0; r < 4; ++r) {
            float e0 = __builtin_amdgcn_exp2f(s00[r] + bc0[r]);
            float e1 = __builtin_amdgcn_exp2f(s01[r] + bc0[4 + r]);
            unsigned u0 = __float_as_uint(e0) + 0x8000u;   // round-half-up
            unsigned u1 = __float_as_uint(e1) + 0x8000u;
            ((unsigned short*)ap0.i4)[r]     = (unsigned short)(u0 >> 16);
            ((unsigned short*)ap0.i4)[4 + r] = (unsigned short)(u1 >> 16);
        }
        #pragma unroll
        for (int r = 0; r < 4; ++r) {
            float e0 = __builtin_amdgcn_exp2f(s10[r] + bc1[r]);
            float e1 = __builtin_amdgcn_exp2f(s11[r] + bc1[4 + r]);
            unsigned u0 = __float_as_uint(e0) + 0x8000u;
            unsigned u1 = __float_as_uint(e1) + 0x8000u;
            ((unsigned short*)ap1.i4)[r]     = (unsigned short)(u0 >> 16);
            ((unsigned short*)ap1.i4)[4 + r] = (unsigned short)(u1 >> 16);
        }

        o00 = __builtin_amdgcn_mfma_f32_16x16x32_bf16(ap0.v, vA0, o00, 0, 0, 0);
        o01 = __builtin_amdgcn_mfma_f32_16x16x32_bf16(ap0.v, vA1, o01, 0, 0, 0);
        ls0 = __builtin_amdgcn_mfma_f32_16x16x32_bf16(ap0.v, ones, ls0, 0, 0, 0);
        o10 = __builtin_amdgcn_mfma_f32_16x16x32_bf16(ap1.v, vA0, o10, 0, 0, 0);
        o11 = __builtin_amdgcn_mfma_f32_16x16x32_bf16(ap1.v, vA1, o11, 0, 0, 0);
        ls1 = __builtin_amdgcn_mfma_f32_16x16x32_bf16(ap1.v, ones, ls1, 0, 0, 0);
    }

    #pragma unroll
    for (int r = 0; r < 4; ++r) {
        float i0 = 1.f / ls0[r], i1 = 1.f / ls1[r];
        o00[r] *= i0; o01[r] *= i0;
        o10[r] *= i1; o11[r] *= i1;
    }

    __syncthreads();   // all waves done with k_s/v_s; overlay otr on k_s region
    unsigned short (*otr)[32][40] = (unsigned short(*)[32][40])smem;
    #pragma unroll
    for (int r = 0; r < 4; ++r) {
        otr[wid][g * 4 + r][ln]           = f2bf(o00[r]);
        otr[wid][g * 4 + r][16 + ln]      = f2bf(o01[r]);
        otr[wid][16 + g * 4 + r][ln]      = f2bf(o10[r]);
        otr[wid][16 + g * 4 + r][16 + ln] = f2bf(o11[r]);
    }
    // same-wave region: DS in-order, no barrier.  2 lanes/row x 16 d each.
    const int row = lane >> 1;
    const int ch  = (lane & 1) * 16;
    uint4 st0 = *(uint4*)&otr[wid][row][ch];
    uint4 st1 = *(uint4*)&otr[wid][row][ch + 8];
    unsigned short* dst = &ao16[((size_t)b * NTOK + qb + row) * CDIM + h * HDIM + ch];
    *(uint4*)dst     = st0;
    *(uint4*)&dst[8] = st1;
}

// ---------------------------------------------------------------------------
// Output projection, bf16 MFMA (round-4 proven form), XCD-swizzled.
// ---------------------------------------------------------------------------
__global__ __launch_bounds__(256) void outproj_kernel(
    const unsigned short* __restrict__ ao16,  // (b,n,256)
    const unsigned short* __restrict__ wo16,  // (256,256)
    const float* __restrict__ bo,
    float* __restrict__ y)                    // (b,256,n)
{
    const int id   = blockIdx.x;
    const int b    = (id & 7) * 2 + ((id >> 3) & 1);
    const int rest = id >> 4;                 // 0..63
    const int ct   = (rest & 3) * 64;
    const int pt   = (rest >> 2) * 64;
    const int t = threadIdx.x, wid = t >> 6, lane = t & 63;
    const int g = lane >> 4, ln = lane & 15;
    const int cbase = ct + wid * 16;
    const unsigned short* ab = ao16 + (size_t)b * NTOK * CDIM;
    f32x4 acc[4];
    #pragma unroll
    for (int i = 0; i < 4; ++i) acc[i] = (f32x4){0.f, 0.f, 0.f, 0.f};

    for (int kt = 0; kt < CDIM; kt += 32) {
        bf16x8 aw = *(const bf16x8*)&wo16[(size_t)(cbase + ln) * CDIM + kt + g * 8];
        #pragma unroll
        for (int t2 = 0; t2 < 4; ++t2) {
            bf16x8 bx = *(const bf16x8*)&ab[(size_t)(pt + t2 * 16 + ln) * CDIM + kt + g * 8];
            acc[t2] = __builtin_amdgcn_mfma_f32_16x16x32_bf16(aw, bx, acc[t2], 0, 0, 0);
        }
    }
    #pragma unroll
    for (int r = 0; r < 4; ++r) {
        const int c = cbase + g * 4 + r;
        const float bias = bo[c];
        #pragma unroll
        for (int t2 = 0; t2 < 4; ++t2)
            y[((size_t)b * CDIM + c) * NTOK + pt + t2 * 16 + ln] = acc[t2][r] + bias;
    }
}

// ---------------------------------------------------------------------------
extern "C" void kernel_launch(void* const* d_in, const int* in_sizes, int n_in,
                              void* d_out, int out_size, void* d_ws, size_t ws_size,
                              hipStream_t stream) {
    const float* x        = (const float*)d_in[0];
    const float* Wq       = (const float*)d_in[1];
    const float* Wk       = (const float*)d_in[2];
    const float* Wv       = (const float*)d_in[3];
    const float* Wo       = (const float*)d_in[4];
    const float* bo       = (const float*)d_in[5];
    const float* rel_bias = (const float*)d_in[6];
    (void)in_sizes; (void)n_in; (void)ws_size; (void)out_size;
    // d_in[7] = rel_idx: unused — bias index computed analytically (j - p + 1056)

    unsigned short* ws16 = (unsigned short*)d_ws;
    unsigned short* xt16 = ws16;                              // 8 MB
    unsigned short* ao16 = ws16 + (size_t)4 * 1024 * 1024;    // 8 MB
    unsigned short* w16  = ws16 + (size_t)8 * 1024 * 1024;    // 512 KB
    float* y = (float*)d_out;

    prep_kernel<<<dim3(16, 4, 17), 256, 0, stream>>>(x, Wq, Wk, Wv, Wo, w16, xt16);
    attn_kernel<<<256, 1024, 0, stream>>>(xt16, w16, rel_bias, ao16);
    outproj_kernel<<<1024, 256, 0, stream>>>(ao16, w16 + 3 * 65536, bo, y);
}

// Round 10
// 172.692 us; speedup vs baseline: 1.4721x; 1.0962x over previous
//
#include <hip/hip_runtime.h>

#define HEADS 8
#define HDIM 32
#define NTOK 1024
#define CDIM 256
#define BATCH 16
#define ATT_SCALE 0.17677669529663687f  // 32^-0.5
#define L2E 1.4426950408889634f
#define VSTR 1032   // v_s row stride (shorts): 2064B, 16B-aligned, 4-bank row rotation
#define BSTR 1540   // bias copy stride (floats): 16B-aligned, +4-bank per copy

typedef __attribute__((ext_vector_type(8))) short bf16x8;   // 8 bf16, 4 VGPRs
typedef __attribute__((ext_vector_type(4))) float f32x4;    // MFMA C/D

__device__ __forceinline__ unsigned short f2bf(float f) {
    unsigned int u = __float_as_uint(f);
    return (unsigned short)((u + 0x7fffu + ((u >> 16) & 1u)) >> 16);  // RNE
}

// K-tile bank swizzle: 16B block cb of row r stored at cb ^ kswz(r).
// Gives 2-way (free) aliasing for the permuted S-tile row sets.
__device__ __forceinline__ int kswz(int row) { return (row + (row >> 3)) & 3; }

// ---------------------------------------------------------------------------
// Prep (fused): z<16 -> x (b,c,n) fp32 -> xt16 (b,n,c) bf16;  z==16 -> weights
// fp32 -> bf16.  Wk pre-scaled by ATT_SCALE*log2(e): S-MFMA output lands in
// log2 domain; bias (also *log2e) rides in the MFMA C operand; exp = v_exp_f32.
// ---------------------------------------------------------------------------
__global__ __launch_bounds__(256) void prep_kernel(
    const float* __restrict__ x,
    const float* __restrict__ Wq, const float* __restrict__ Wk,
    const float* __restrict__ Wv, const float* __restrict__ Wo,
    unsigned short* __restrict__ w16, unsigned short* __restrict__ xt16)
{
    const int t = threadIdx.x;
    if (blockIdx.z == 16) {
        const int which = blockIdx.y;
        const float* src = (which == 0) ? Wq : ((which == 1) ? Wk : ((which == 2) ? Wv : Wo));
        const float scale = (which == 1) ? (ATT_SCALE * L2E) : 1.0f;
        const int base = (blockIdx.x * 256 + t) * 16;
        #pragma unroll
        for (int i = 0; i < 4; ++i) {
            const int idx = base + i * 4;
            float4 v = *(const float4*)&src[idx];
            union { unsigned short h[4]; uint2 u; } pk;
            pk.h[0] = f2bf(v.x * scale); pk.h[1] = f2bf(v.y * scale);
            pk.h[2] = f2bf(v.z * scale); pk.h[3] = f2bf(v.w * scale);
            *(uint2*)&w16[(size_t)which * 65536 + idx] = pk.u;
        }
        return;
    }
    __shared__ float tile[64][65];
    const int b = blockIdx.z, ct = blockIdx.y * 64, nt = blockIdx.x * 64;
    const float* xb = x + ((size_t)b * CDIM + ct) * NTOK + nt;
    const int cc = t >> 4, n4 = (t & 15) * 4;
    #pragma unroll
    for (int i = 0; i < 4; ++i) {
        float4 v = *(const float4*)&xb[(size_t)(cc + 16 * i) * NTOK + n4];
        tile[cc + 16 * i][n4]     = v.x;
        tile[cc + 16 * i][n4 + 1] = v.y;
        tile[cc + 16 * i][n4 + 2] = v.z;
        tile[cc + 16 * i][n4 + 3] = v.w;
    }
    __syncthreads();
    const int c0 = (t & 15) * 4;
    #pragma unroll
    for (int i = 0; i < 4; ++i) {
        const int nl = (t >> 4) + 16 * i;
        union { unsigned short h[4]; uint2 u; } pk;
        #pragma unroll
        for (int j = 0; j < 4; ++j) pk.h[j] = f2bf(tile[c0 + j][nl]);
        *(uint2*)&xt16[((size_t)b * NTOK + nt + nl) * CDIM + ct + c0] = pk.u;
    }
}

// ---------------------------------------------------------------------------
// Fused QKV + flash attention.  Block = (b, h, query-half): 1024 thr/16 waves.
//  Stage 1: Q GEMM (q_s overlay on V region, same-wave readback) -> barrier ->
//  fused K+V GEMM sharing x fragments (x read once; 8 loads / 16 MFMA per kt).
//  K stored XOR-swizzled; V stored with VSTR rotation.
//  Stage 2 (32 iters, zero global / zero barriers): K/V via ds_read_b128,
//  bias*log2e via 4 shift-aligned LDS copies read as the S-MFMA C operand,
//  P register-resident (S^T permutation trick), row-sums via MFMA vs ones.
//  FIX (R9->R10): P pack must be [e0[0..3] | e1[0..3]] (8 consecutive keys
//  kb+8g+0..7); R9's perm paired ACROSS tiles -> interleaved k-slots -> wrong
//  PV product (absmax 2.6e-2).  Pack now pairs within each tile.
// ---------------------------------------------------------------------------
__global__ __launch_bounds__(1024, 4) void attn_kernel(
    const unsigned short* __restrict__ xt16,  // (b,n,c) bf16
    const unsigned short* __restrict__ w16,   // wq|wk|wv|wo (wk pre-scaled)
    const float* __restrict__ rel_bias,       // (h, 3969)
    unsigned short* __restrict__ ao16)        // (b, n, 256)
{
    __shared__ __align__(16) unsigned char smem[65536 + VSTR * 32 * 2 + BSTR * 4 * 4];
    unsigned short* k_s   = (unsigned short*)smem;                    // 1024 rows x 32 (swizzled)
    unsigned short* v_s   = (unsigned short*)(smem + 65536);          // 32 x VSTR
    unsigned short* q_s   = (unsigned short*)(smem + 65536);          // overlay (512 x 32)
    float*          bias4 = (float*)(smem + 65536 + VSTR * 32 * 2);   // [4][BSTR]

    const int id   = blockIdx.x;                    // 0..255
    const int bh_i = (id & 7) * 16 + (id >> 4);     // XCD x owns bh [16x,16x+16)
    const int half = (id >> 3) & 1;
    const int b = bh_i >> 3, h = bh_i & 7;

    const int t = threadIdx.x, wid = t >> 6, lane = t & 63;
    const int g = lane >> 4, ln = lane & 15;
    const int qb = half * 512 + wid * 32;           // wave's 32 queries

    const unsigned short* xb  = xt16 + (size_t)b * NTOK * CDIM;
    const unsigned short* wqh = w16 + (size_t)(h * 32) * CDIM;
    const unsigned short* wkh = w16 + 65536 + (size_t)(h * 32) * CDIM;
    const unsigned short* wvh = w16 + 2 * 65536 + (size_t)(h * 32) * CDIM;

    // ---- bias*log2e -> 4 shift-aligned copies, trimmed to this block's range ----
    // Needed global idx range: [START+1, START+1535]; loads stay < 3969. ----
    {
        const int START = 544 - 512 * half;         // 4-aligned window base
        const float* brow = rel_bias + (size_t)h * 3969;
        for (int i = t; i < 1540; i += 1024) {
            #pragma unroll
            for (int a = 0; a < 4; ++a)
                bias4[a * BSTR + i] = brow[START + a + i] * L2E;
        }
    }

    // ---- Stage 1a: Q GEMM — rows [qb,+32); write+read via q_s (same wave) ----
    bf16x8 aq0, aq1;
    {
        f32x4 acc[2][2];
        #pragma unroll
        for (int m = 0; m < 2; ++m)
            #pragma unroll
            for (int n = 0; n < 2; ++n) acc[m][n] = (f32x4){0.f, 0.f, 0.f, 0.f};
        #pragma unroll
        for (int kt = 0; kt < CDIM; kt += 32) {
            bf16x8 a[2], w2[2];
            #pragma unroll
            for (int m = 0; m < 2; ++m)
                a[m] = *(const bf16x8*)&xb[(size_t)(qb + m * 16 + ln) * CDIM + kt + g * 8];
            #pragma unroll
            for (int n = 0; n < 2; ++n)
                w2[n] = *(const bf16x8*)&wqh[(size_t)(n * 16 + ln) * CDIM + kt + g * 8];
            #pragma unroll
            for (int m = 0; m < 2; ++m)
                #pragma unroll
                for (int n = 0; n < 2; ++n)
                    acc[m][n] = __builtin_amdgcn_mfma_f32_16x16x32_bf16(a[m], w2[n], acc[m][n], 0, 0, 0);
        }
        const int lr = wid * 32;
        #pragma unroll
        for (int m = 0; m < 2; ++m)
            #pragma unroll
            for (int n = 0; n < 2; ++n)
                #pragma unroll
                for (int r = 0; r < 4; ++r)
                    q_s[(size_t)(lr + m * 16 + g * 4 + r) * HDIM + n * 16 + ln] = f2bf(acc[m][n][r]);
        aq0 = *(const bf16x8*)&q_s[(size_t)(lr + ln) * HDIM + g * 8];
        aq1 = *(const bf16x8*)&q_s[(size_t)(lr + 16 + ln) * HDIM + g * 8];
    }

    __syncthreads();   // all q_s reads done before V overwrites the region

    // ---- Stage 1b: fused K+V GEMM — shared x fragments, tokens [wid*64,+64) ----
    {
        const int tr = wid * 64;
        f32x4 ak[4][2], av[2][4];
        #pragma unroll
        for (int m = 0; m < 4; ++m)
            #pragma unroll
            for (int n = 0; n < 2; ++n) {
                ak[m][n] = (f32x4){0.f, 0.f, 0.f, 0.f};
                av[n][m] = (f32x4){0.f, 0.f, 0.f, 0.f};
            }
        #pragma unroll
        for (int kt = 0; kt < CDIM; kt += 32) {
            bf16x8 xf[4], wkf[2], wvf[2];
            #pragma unroll
            for (int m = 0; m < 4; ++m)
                xf[m] = *(const bf16x8*)&xb[(size_t)(tr + m * 16 + ln) * CDIM + kt + g * 8];
            #pragma unroll
            for (int n = 0; n < 2; ++n) {
                wkf[n] = *(const bf16x8*)&wkh[(size_t)(n * 16 + ln) * CDIM + kt + g * 8];
                wvf[n] = *(const bf16x8*)&wvh[(size_t)(n * 16 + ln) * CDIM + kt + g * 8];
            }
            #pragma unroll
            for (int m = 0; m < 4; ++m) {
                ak[m][0] = __builtin_amdgcn_mfma_f32_16x16x32_bf16(xf[m], wkf[0], ak[m][0], 0, 0, 0);
                ak[m][1] = __builtin_amdgcn_mfma_f32_16x16x32_bf16(xf[m], wkf[1], ak[m][1], 0, 0, 0);
                av[0][m] = __builtin_amdgcn_mfma_f32_16x16x32_bf16(wvf[0], xf[m], av[0][m], 0, 0, 0);
                av[1][m] = __builtin_amdgcn_mfma_f32_16x16x32_bf16(wvf[1], xf[m], av[1][m], 0, 0, 0);
            }
        }
        // K store: row = token, swizzled 16B blocks
        #pragma unroll
        for (int m = 0; m < 4; ++m)
            #pragma unroll
            for (int n = 0; n < 2; ++n)
                #pragma unroll
                for (int r = 0; r < 4; ++r) {
                    const int row = tr + m * 16 + g * 4 + r;
                    const int col = n * 16 + ln;
                    k_s[row * 32 + (((col >> 3) ^ kswz(row)) << 3) + (col & 7)] = f2bf(ak[m][n][r]);
                }
        // V store: row = d, rotated stride
        #pragma unroll
        for (int n = 0; n < 2; ++n)
            #pragma unroll
            for (int m = 0; m < 4; ++m)
                #pragma unroll
                for (int r = 0; r < 4; ++r)
                    v_s[(size_t)(n * 16 + g * 4 + r) * VSTR + tr + m * 16 + ln] = f2bf(av[n][m][r]);
    }

    __syncthreads();   // K, V, bias all LDS-resident

    // ---- Stage 2: attention main loop ----
    const int jrow = 8 * (ln >> 2) + (ln & 3);       // permuted K-row (tile 0)
    const int jr1  = jrow + 4;
    const int koff0 = jrow * 32 + ((g ^ kswz(jrow)) << 3);   // kb-invariant (kb%32==0)
    const int koff1 = jr1 * 32 + ((g ^ kswz(jr1)) << 3);
    const int boffL = 512 + 8 * g - wid * 32 - ln;   // local bias offset (half-invariant)
    const int ba = boffL & 3;
    const float* bb = &bias4[ba * BSTR + (boffL - ba)];
    const unsigned short* vr0 = &v_s[(size_t)ln * VSTR + g * 8];
    const unsigned short* vr1 = &v_s[(size_t)(16 + ln) * VSTR + g * 8];

    f32x4 o00 = {0.f,0.f,0.f,0.f}, o01 = {0.f,0.f,0.f,0.f};
    f32x4 o10 = {0.f,0.f,0.f,0.f}, o11 = {0.f,0.f,0.f,0.f};
    f32x4 ls0 = {0.f,0.f,0.f,0.f}, ls1 = {0.f,0.f,0.f,0.f};
    const short one_bf = (short)0x3F80;
    const bf16x8 ones = {one_bf,one_bf,one_bf,one_bf,one_bf,one_bf,one_bf,one_bf};

    for (int kb = 0; kb < NTOK; kb += 32) {
        const bf16x8 kf0 = *(const bf16x8*)&k_s[kb * 32 + koff0];
        const bf16x8 kf1 = *(const bf16x8*)&k_s[kb * 32 + koff1];
        const bf16x8 vA0 = *(const bf16x8*)&vr0[kb];
        const bf16x8 vA1 = *(const bf16x8*)&vr1[kb];
        const f32x4 cA0 = *(const f32x4*)&bb[kb];
        const f32x4 cA1 = *(const f32x4*)&bb[kb + 4];
        const f32x4 cB0 = *(const f32x4*)&bb[kb - 16];
        const f32x4 cB1 = *(const f32x4*)&bb[kb - 12];

        f32x4 s00 = __builtin_amdgcn_mfma_f32_16x16x32_bf16(kf0, aq0, cA0, 0, 0, 0);
        f32x4 s01 = __builtin_amdgcn_mfma_f32_16x16x32_bf16(kf1, aq0, cA1, 0, 0, 0);
        f32x4 s10 = __builtin_amdgcn_mfma_f32_16x16x32_bf16(kf0, aq1, cB0, 0, 0, 0);
        f32x4 s11 = __builtin_amdgcn_mfma_f32_16x16x32_bf16(kf1, aq1, cB1, 0, 0, 0);

        // Pack P: shorts [e(s0[0..3]) | e(s1[0..3])] = keys kb+8g+0..7 in order.
        union { unsigned u4[4]; bf16x8 v; } ap0, ap1;
        #pragma unroll
        for (int p2 = 0; p2 < 2; ++p2) {
            unsigned ua = __float_as_uint(__builtin_amdgcn_exp2f(s00[2 * p2]))     + 0x8000u;
            unsigned ub = __float_as_uint(__builtin_amdgcn_exp2f(s00[2 * p2 + 1])) + 0x8000u;
            ap0.u4[p2]     = (ub & 0xffff0000u) | (ua >> 16);
            unsigned uc = __float_as_uint(__builtin_amdgcn_exp2f(s01[2 * p2]))     + 0x8000u;
            unsigned ud = __float_as_uint(__builtin_amdgcn_exp2f(s01[2 * p2 + 1])) + 0x8000u;
            ap0.u4[2 + p2] = (ud & 0xffff0000u) | (uc >> 16);
        }
        #pragma unroll
        for (int p2 = 0; p2 < 2; ++p2) {
            unsigned ua = __float_as_uint(__builtin_amdgcn_exp2f(s10[2 * p2]))     + 0x8000u;
            unsigned ub = __float_as_uint(__builtin_amdgcn_exp2f(s10[2 * p2 + 1])) + 0x8000u;
            ap1.u4[p2]     = (ub & 0xffff0000u) | (ua >> 16);
            unsigned uc = __float_as_uint(__builtin_amdgcn_exp2f(s11[2 * p2]))     + 0x8000u;
            unsigned ud = __float_as_uint(__builtin_amdgcn_exp2f(s11[2 * p2 + 1])) + 0x8000u;
            ap1.u4[2 + p2] = (ud & 0xffff0000u) | (uc >> 16);
        }

        o00 = __builtin_amdgcn_mfma_f32_16x16x32_bf16(ap0.v, vA0, o00, 0, 0, 0);
        o01 = __builtin_amdgcn_mfma_f32_16x16x32_bf16(ap0.v, vA1, o01, 0, 0, 0);
        ls0 = __builtin_amdgcn_mfma_f32_16x16x32_bf16(ap0.v, ones, ls0, 0, 0, 0);
        o10 = __builtin_amdgcn_mfma_f32_16x16x32_bf16(ap1.v, vA0, o10, 0, 0, 0);
        o11 = __builtin_amdgcn_mfma_f32_16x16x32_bf16(ap1.v, vA1, o11, 0, 0, 0);
        ls1 = __builtin_amdgcn_mfma_f32_16x16x32_bf16(ap1.v, ones, ls1, 0, 0, 0);
    }

    #pragma unroll
    for (int r = 0; r < 4; ++r) {
        float i0 = 1.f / ls0[r], i1 = 1.f / ls1[r];
        o00[r] *= i0; o01[r] *= i0;
        o10[r] *= i1; o11[r] *= i1;
    }

    __syncthreads();   // all waves done with k_s; overlay otr on K region
    unsigned short (*otr)[32][40] = (unsigned short(*)[32][40])smem;
    #pragma unroll
    for (int r = 0; r < 4; ++r) {
        otr[wid][g * 4 + r][ln]           = f2bf(o00[r]);
        otr[wid][g * 4 + r][16 + ln]      = f2bf(o01[r]);
        otr[wid][16 + g * 4 + r][ln]      = f2bf(o10[r]);
        otr[wid][16 + g * 4 + r][16 + ln] = f2bf(o11[r]);
    }
    // same-wave region: DS in-order, no barrier.  2 lanes/row x 16 d each.
    const int row = lane >> 1;
    const int ch  = (lane & 1) * 16;
    uint4 st0 = *(uint4*)&otr[wid][row][ch];
    uint4 st1 = *(uint4*)&otr[wid][row][ch + 8];
    unsigned short* dst = &ao16[((size_t)b * NTOK + qb + row) * CDIM + h * HDIM + ch];
    *(uint4*)dst     = st0;
    *(uint4*)&dst[8] = st1;
}

// ---------------------------------------------------------------------------
// Output projection: 64c x 128p per block, wave = 2 c-frags x 4 p-frags.
// XCD-swizzled flat grid 512.
// ---------------------------------------------------------------------------
__global__ __launch_bounds__(256) void outproj_kernel(
    const unsigned short* __restrict__ ao16,  // (b,n,256)
    const unsigned short* __restrict__ wo16,  // (256,256)
    const float* __restrict__ bo,
    float* __restrict__ y)                    // (b,256,n)
{
    const int id   = blockIdx.x;              // 0..511
    const int b    = (id & 7) * 2 + ((id >> 3) & 1);
    const int rest = id >> 4;                 // 0..31
    const int ct   = (rest & 3) * 64;
    const int pt   = (rest >> 2) * 128;
    const int t = threadIdx.x, wid = t >> 6, lane = t & 63;
    const int g = lane >> 4, ln = lane & 15;
    const int cb2 = ct + (wid & 1) * 32;
    const int pb  = pt + (wid >> 1) * 64;
    const unsigned short* ab = ao16 + (size_t)b * NTOK * CDIM;

    f32x4 acc[2][4];
    #pragma unroll
    for (int n = 0; n < 2; ++n)
        #pragma unroll
        for (int m = 0; m < 4; ++m) acc[n][m] = (f32x4){0.f, 0.f, 0.f, 0.f};

    #pragma unroll
    for (int kt = 0; kt < CDIM; kt += 32) {
        bf16x8 aw[2], bx[4];
        #pragma unroll
        for (int n = 0; n < 2; ++n)
            aw[n] = *(const bf16x8*)&wo16[(size_t)(cb2 + n * 16 + ln) * CDIM + kt + g * 8];
        #pragma unroll
        for (int m = 0; m < 4; ++m)
            bx[m] = *(const bf16x8*)&ab[(size_t)(pb + m * 16 + ln) * CDIM + kt + g * 8];
        #pragma unroll
        for (int n = 0; n < 2; ++n)
            #pragma unroll
            for (int m = 0; m < 4; ++m)
                acc[n][m] = __builtin_amdgcn_mfma_f32_16x16x32_bf16(aw[n], bx[m], acc[n][m], 0, 0, 0);
    }
    #pragma unroll
    for (int n = 0; n < 2; ++n)
        #pragma unroll
        for (int r = 0; r < 4; ++r) {
            const int c = cb2 + n * 16 + g * 4 + r;
            const float bias = bo[c];
            #pragma unroll
            for (int m = 0; m < 4; ++m)
                y[((size_t)b * CDIM + c) * NTOK + pb + m * 16 + ln] = acc[n][m][r] + bias;
        }
}

// ---------------------------------------------------------------------------
extern "C" void kernel_launch(void* const* d_in, const int* in_sizes, int n_in,
                              void* d_out, int out_size, void* d_ws, size_t ws_size,
                              hipStream_t stream) {
    const float* x        = (const float*)d_in[0];
    const float* Wq       = (const float*)d_in[1];
    const float* Wk       = (const float*)d_in[2];
    const float* Wv       = (const float*)d_in[3];
    const float* Wo       = (const float*)d_in[4];
    const float* bo       = (const float*)d_in[5];
    const float* rel_bias = (const float*)d_in[6];
    (void)in_sizes; (void)n_in; (void)ws_size; (void)out_size;
    // d_in[7] = rel_idx: unused — bias index computed analytically (j - p + 1056)

    unsigned short* ws16 = (unsigned short*)d_ws;
    unsigned short* xt16 = ws16;                              // 8 MB
    unsigned short* ao16 = ws16 + (size_t)4 * 1024 * 1024;    // 8 MB
    unsigned short* w16  = ws16 + (size_t)8 * 1024 * 1024;    // 512 KB
    float* y = (float*)d_out;

    prep_kernel<<<dim3(16, 4, 17), 256, 0, stream>>>(x, Wq, Wk, Wv, Wo, w16, xt16);
    attn_kernel<<<256, 1024, 0, stream>>>(xt16, w16, rel_bias, ao16);
    outproj_kernel<<<512, 256, 0, stream>>>(ao16, w16 + 3 * 65536, bo, y);
}

// Round 11
// 168.527 us; speedup vs baseline: 1.5084x; 1.0247x over previous
//
#include <hip/hip_runtime.h>

#define HEADS 8
#define HDIM 32
#define NTOK 1024
#define CDIM 256
#define BATCH 16
#define ATT_SCALE 0.17677669529663687f  // 32^-0.5
#define L2E 1.4426950408889634f
#define BSTR 1544   // bias copy stride (floats): 16B-aligned; 1544%32=8 -> ~2-way reads

typedef __attribute__((ext_vector_type(8))) short bf16x8;   // 8 bf16, 4 VGPRs
typedef __attribute__((ext_vector_type(4))) float f32x4;    // MFMA C/D

__device__ __forceinline__ unsigned short f2bf(float f) {
    unsigned int u = __float_as_uint(f);
    return (unsigned short)((u + 0x7fffu + ((u >> 16) & 1u)) >> 16);  // RNE
}

// ---------------------------------------------------------------------------
// Prep (fused): z<16 -> x (b,c,n) fp32 -> xt16 (b,n,c) bf16;  z==16 -> weights
// fp32 -> bf16.  Wk pre-scaled by ATT_SCALE*log2(e): S-MFMA output lands in
// log2 domain; bias (also *log2e) rides in the MFMA C operand; exp = v_exp_f32.
// ---------------------------------------------------------------------------
__global__ __launch_bounds__(256) void prep_kernel(
    const float* __restrict__ x,
    const float* __restrict__ Wq, const float* __restrict__ Wk,
    const float* __restrict__ Wv, const float* __restrict__ Wo,
    unsigned short* __restrict__ w16, unsigned short* __restrict__ xt16)
{
    const int t = threadIdx.x;
    if (blockIdx.z == 16) {
        const int which = blockIdx.y;
        const float* src = (which == 0) ? Wq : ((which == 1) ? Wk : ((which == 2) ? Wv : Wo));
        const float scale = (which == 1) ? (ATT_SCALE * L2E) : 1.0f;
        const int base = (blockIdx.x * 256 + t) * 16;
        #pragma unroll
        for (int i = 0; i < 4; ++i) {
            const int idx = base + i * 4;
            float4 v = *(const float4*)&src[idx];
            union { unsigned short h[4]; uint2 u; } pk;
            pk.h[0] = f2bf(v.x * scale); pk.h[1] = f2bf(v.y * scale);
            pk.h[2] = f2bf(v.z * scale); pk.h[3] = f2bf(v.w * scale);
            *(uint2*)&w16[(size_t)which * 65536 + idx] = pk.u;
        }
        return;
    }
    __shared__ float tile[64][65];
    const int b = blockIdx.z, ct = blockIdx.y * 64, nt = blockIdx.x * 64;
    const float* xb = x + ((size_t)b * CDIM + ct) * NTOK + nt;
    const int cc = t >> 4, n4 = (t & 15) * 4;
    #pragma unroll
    for (int i = 0; i < 4; ++i) {
        float4 v = *(const float4*)&xb[(size_t)(cc + 16 * i) * NTOK + n4];
        tile[cc + 16 * i][n4]     = v.x;
        tile[cc + 16 * i][n4 + 1] = v.y;
        tile[cc + 16 * i][n4 + 2] = v.z;
        tile[cc + 16 * i][n4 + 3] = v.w;
    }
    __syncthreads();
    const int c0 = (t & 7) * 8;          // 8 c-values per 16B store
    #pragma unroll
    for (int i = 0; i < 2; ++i) {
        const int nl = (t >> 3) + 32 * i;
        union { unsigned short h[8]; uint4 u; } pk;
        #pragma unroll
        for (int j = 0; j < 8; ++j) pk.h[j] = f2bf(tile[c0 + j][nl]);
        *(uint4*)&xt16[((size_t)b * NTOK + nt + nl) * CDIM + ct + c0] = pk.u;
    }
}

// ---------------------------------------------------------------------------
// Fused QKV + flash attention.  Block = (b, h, query-half): 1024 thr/16 waves.
//  Stage 1: Q GEMM (q_s overlay on V region, same-wave readback) -> barrier ->
//  fused K+V GEMM sharing x fragments.  K and V are stored FRAGMENT-MAJOR:
//  the 16B fragment that lane l reads for (kb-block, tile/half) lives at
//  frag*1024 + l*16 bytes -> stage-2 reads are linear in lane = ZERO bank
//  conflicts by construction (replaces R10's ineffective kswz + VSTR).
//  Stage 2 (32 iters, zero global / zero barriers): K/V via linear
//  ds_read_b128, bias*log2e via 4 shift-aligned LDS copies as the S-MFMA C
//  operand, P register-resident (S^T permutation), row-sums via MFMA vs ones.
//  Fragment algebra (verified both directions on K[37][5], V[5][37]):
//   K read (lane g,ln, tile t, block kb): K[kb + 8*(ln>>2)+(ln&3) + 4t][8g..+8)
//   K elem (row,col) -> frag=(row>>5)*2+((row>>2)&1),
//     lane'=(2*(col>>4... col>>3))*16? see store loop; addr=frag*512+lane'*8+(col&7)
//   V read (lane g,ln, half hf): V[d=16hf+ln][kb+8g..+8)
// ---------------------------------------------------------------------------
__global__ __launch_bounds__(1024, 4) void attn_kernel(
    const unsigned short* __restrict__ xt16,  // (b,n,c) bf16
    const unsigned short* __restrict__ w16,   // wq|wk|wv|wo (wk pre-scaled)
    const float* __restrict__ rel_bias,       // (h, 3969)
    unsigned short* __restrict__ ao16)        // (b, n, 256)
{
    __shared__ __align__(16) unsigned char smem[65536 + 65536 + BSTR * 4 * 4];
    unsigned short* k_s   = (unsigned short*)smem;             // 64 frags x 512 shorts
    unsigned short* v_s   = (unsigned short*)(smem + 65536);   // 64 frags x 512 shorts
    unsigned short* q_s   = (unsigned short*)(smem + 65536);   // overlay (512 x 32)
    float*          bias4 = (float*)(smem + 131072);           // [4][BSTR]

    const int id   = blockIdx.x;                    // 0..255
    const int bh_i = (id & 7) * 16 + (id >> 4);     // XCD x owns bh [16x,16x+16)
    const int half = (id >> 3) & 1;
    const int b = bh_i >> 3, h = bh_i & 7;

    const int t = threadIdx.x, wid = t >> 6, lane = t & 63;
    const int g = lane >> 4, ln = lane & 15;
    const int qb = half * 512 + wid * 32;           // wave's 32 queries

    const unsigned short* xb  = xt16 + (size_t)b * NTOK * CDIM;
    const unsigned short* wqh = w16 + (size_t)(h * 32) * CDIM;
    const unsigned short* wkh = w16 + 65536 + (size_t)(h * 32) * CDIM;
    const unsigned short* wvh = w16 + 2 * 65536 + (size_t)(h * 32) * CDIM;

    // ---- bias*log2e -> 4 shift-aligned copies, trimmed to this block's range ----
    {
        const int START = 544 - 512 * half;         // 4-aligned window base
        const float* brow = rel_bias + (size_t)h * 3969;
        for (int i = t; i < 1540; i += 1024) {
            #pragma unroll
            for (int a = 0; a < 4; ++a)
                bias4[a * BSTR + i] = brow[START + a + i] * L2E;
        }
    }

    // ---- Stage 1a: Q GEMM — rows [qb,+32); write+read via q_s (same wave) ----
    bf16x8 aq0, aq1;
    {
        f32x4 acc[2][2];
        #pragma unroll
        for (int m = 0; m < 2; ++m)
            #pragma unroll
            for (int n = 0; n < 2; ++n) acc[m][n] = (f32x4){0.f, 0.f, 0.f, 0.f};
        #pragma unroll
        for (int kt = 0; kt < CDIM; kt += 32) {
            bf16x8 a[2], w2[2];
            #pragma unroll
            for (int m = 0; m < 2; ++m)
                a[m] = *(const bf16x8*)&xb[(size_t)(qb + m * 16 + ln) * CDIM + kt + g * 8];
            #pragma unroll
            for (int n = 0; n < 2; ++n)
                w2[n] = *(const bf16x8*)&wqh[(size_t)(n * 16 + ln) * CDIM + kt + g * 8];
            #pragma unroll
            for (int m = 0; m < 2; ++m)
                #pragma unroll
                for (int n = 0; n < 2; ++n)
                    acc[m][n] = __builtin_amdgcn_mfma_f32_16x16x32_bf16(a[m], w2[n], acc[m][n], 0, 0, 0);
        }
        const int lr = wid * 32;
        #pragma unroll
        for (int m = 0; m < 2; ++m)
            #pragma unroll
            for (int n = 0; n < 2; ++n)
                #pragma unroll
                for (int r = 0; r < 4; ++r)
                    q_s[(size_t)(lr + m * 16 + g * 4 + r) * HDIM + n * 16 + ln] = f2bf(acc[m][n][r]);
        aq0 = *(const bf16x8*)&q_s[(size_t)(lr + ln) * HDIM + g * 8];
        aq1 = *(const bf16x8*)&q_s[(size_t)(lr + 16 + ln) * HDIM + g * 8];
    }

    __syncthreads();   // all q_s reads done before V overwrites the region

    // ---- Stage 1b: fused K+V GEMM — shared x fragments, tokens [wid*64,+64) ----
    {
        const int tr = wid * 64;
        f32x4 ak[4][2], av[2][4];
        #pragma unroll
        for (int m = 0; m < 4; ++m)
            #pragma unroll
            for (int n = 0; n < 2; ++n) {
                ak[m][n] = (f32x4){0.f, 0.f, 0.f, 0.f};
                av[n][m] = (f32x4){0.f, 0.f, 0.f, 0.f};
            }
        #pragma unroll
        for (int kt = 0; kt < CDIM; kt += 32) {
            bf16x8 xf[4], wkf[2], wvf[2];
            #pragma unroll
            for (int m = 0; m < 4; ++m)
                xf[m] = *(const bf16x8*)&xb[(size_t)(tr + m * 16 + ln) * CDIM + kt + g * 8];
            #pragma unroll
            for (int n = 0; n < 2; ++n) {
                wkf[n] = *(const bf16x8*)&wkh[(size_t)(n * 16 + ln) * CDIM + kt + g * 8];
                wvf[n] = *(const bf16x8*)&wvh[(size_t)(n * 16 + ln) * CDIM + kt + g * 8];
            }
            #pragma unroll
            for (int m = 0; m < 4; ++m) {
                ak[m][0] = __builtin_amdgcn_mfma_f32_16x16x32_bf16(xf[m], wkf[0], ak[m][0], 0, 0, 0);
                ak[m][1] = __builtin_amdgcn_mfma_f32_16x16x32_bf16(xf[m], wkf[1], ak[m][1], 0, 0, 0);
                av[0][m] = __builtin_amdgcn_mfma_f32_16x16x32_bf16(wvf[0], xf[m], av[0][m], 0, 0, 0);
                av[1][m] = __builtin_amdgcn_mfma_f32_16x16x32_bf16(wvf[1], xf[m], av[1][m], 0, 0, 0);
            }
        }
        // K store, fragment-major.  ak[m][n][r] = K[row=tr+m*16+g*4+r][col=n*16+ln].
        //   frag = (row>>5)*2 + (g&1);  ln' = ((m&1)*2 + (g>>1))*4 + r;
        //   lane' = (2n + (ln>>3))*16 + ln';  addr = frag*512 + lane'*8 + (ln&7).
        #pragma unroll
        for (int m = 0; m < 4; ++m) {
            const int fbase = (2 * wid + (m >> 1)) * 2 + (g & 1);
            #pragma unroll
            for (int n = 0; n < 2; ++n) {
                const int lhi = (2 * n + (ln >> 3)) * 16 + ((m & 1) * 2 + (g >> 1)) * 4;
                #pragma unroll
                for (int r = 0; r < 4; ++r)
                    k_s[fbase * 512 + (lhi + r) * 8 + (ln & 7)] = f2bf(ak[m][n][r]);
            }
        }
        // V store, fragment-major.  av[n][m][r] = V[d=n*16+g*4+r][tok=tr+m*16+ln].
        //   frag = (tok>>5)*2 + n;  lane'' = ((m&1)*2 + (ln>>3))*16 + g*4+r;
        //   addr = frag*512 + lane''*8 + (ln&7).
        #pragma unroll
        for (int n = 0; n < 2; ++n)
            #pragma unroll
            for (int m = 0; m < 4; ++m) {
                const int fr  = (2 * wid + (m >> 1)) * 2 + n;
                const int lnb = ((m & 1) * 2 + (ln >> 3)) * 16 + g * 4;
                #pragma unroll
                for (int r = 0; r < 4; ++r)
                    v_s[fr * 512 + (lnb + r) * 8 + (ln & 7)] = f2bf(av[n][m][r]);
            }
    }

    __syncthreads();   // K, V, bias all LDS-resident

    // ---- Stage 2: attention main loop (linear lane-addressed LDS reads) ----
    const int boffL = 512 + 8 * g - wid * 32 - ln;   // local bias offset
    const int ba = boffL & 3;
    const float* bb = &bias4[ba * BSTR + (boffL - ba)];
    const unsigned short* kfp = k_s + lane * 8;      // frag stride 512 shorts
    const unsigned short* vfp = v_s + lane * 8;

    f32x4 o00 = {0.f,0.f,0.f,0.f}, o01 = {0.f,0.f,0.f,0.f};
    f32x4 o10 = {0.f,0.f,0.f,0.f}, o11 = {0.f,0.f,0.f,0.f};
    f32x4 ls0 = {0.f,0.f,0.f,0.f}, ls1 = {0.f,0.f,0.f,0.f};
    const short one_bf = (short)0x3F80;
    const bf16x8 ones = {one_bf,one_bf,one_bf,one_bf,one_bf,one_bf,one_bf,one_bf};

    for (int kb = 0; kb < NTOK; kb += 32) {
        const int fi = (kb >> 5) * 2;
        const bf16x8 kf0 = *(const bf16x8*)&kfp[fi * 512];
        const bf16x8 kf1 = *(const bf16x8*)&kfp[(fi + 1) * 512];
        const bf16x8 vA0 = *(const bf16x8*)&vfp[fi * 512];
        const bf16x8 vA1 = *(const bf16x8*)&vfp[(fi + 1) * 512];
        const f32x4 cA0 = *(const f32x4*)&bb[kb];
        const f32x4 cA1 = *(const f32x4*)&bb[kb + 4];
        const f32x4 cB0 = *(const f32x4*)&bb[kb - 16];
        const f32x4 cB1 = *(const f32x4*)&bb[kb - 12];

        f32x4 s00 = __builtin_amdgcn_mfma_f32_16x16x32_bf16(kf0, aq0, cA0, 0, 0, 0);
        f32x4 s01 = __builtin_amdgcn_mfma_f32_16x16x32_bf16(kf1, aq0, cA1, 0, 0, 0);
        f32x4 s10 = __builtin_amdgcn_mfma_f32_16x16x32_bf16(kf0, aq1, cB0, 0, 0, 0);
        f32x4 s11 = __builtin_amdgcn_mfma_f32_16x16x32_bf16(kf1, aq1, cB1, 0, 0, 0);

        // Pack P: shorts [e(s0[0..3]) | e(s1[0..3])] = keys kb+8g+0..7 in order.
        union { unsigned u4[4]; bf16x8 v; } ap0, ap1;
        #pragma unroll
        for (int p2 = 0; p2 < 2; ++p2) {
            unsigned ua = __float_as_uint(__builtin_amdgcn_exp2f(s00[2 * p2]))     + 0x8000u;
            unsigned ub = __float_as_uint(__builtin_amdgcn_exp2f(s00[2 * p2 + 1])) + 0x8000u;
            ap0.u4[p2]     = (ub & 0xffff0000u) | (ua >> 16);
            unsigned uc = __float_as_uint(__builtin_amdgcn_exp2f(s01[2 * p2]))     + 0x8000u;
            unsigned ud = __float_as_uint(__builtin_amdgcn_exp2f(s01[2 * p2 + 1])) + 0x8000u;
            ap0.u4[2 + p2] = (ud & 0xffff0000u) | (uc >> 16);
        }
        #pragma unroll
        for (int p2 = 0; p2 < 2; ++p2) {
            unsigned ua = __float_as_uint(__builtin_amdgcn_exp2f(s10[2 * p2]))     + 0x8000u;
            unsigned ub = __float_as_uint(__builtin_amdgcn_exp2f(s10[2 * p2 + 1])) + 0x8000u;
            ap1.u4[p2]     = (ub & 0xffff0000u) | (ua >> 16);
            unsigned uc = __float_as_uint(__builtin_amdgcn_exp2f(s11[2 * p2]))     + 0x8000u;
            unsigned ud = __float_as_uint(__builtin_amdgcn_exp2f(s11[2 * p2 + 1])) + 0x8000u;
            ap1.u4[2 + p2] = (ud & 0xffff0000u) | (uc >> 16);
        }

        o00 = __builtin_amdgcn_mfma_f32_16x16x32_bf16(ap0.v, vA0, o00, 0, 0, 0);
        o01 = __builtin_amdgcn_mfma_f32_16x16x32_bf16(ap0.v, vA1, o01, 0, 0, 0);
        ls0 = __builtin_amdgcn_mfma_f32_16x16x32_bf16(ap0.v, ones, ls0, 0, 0, 0);
        o10 = __builtin_amdgcn_mfma_f32_16x16x32_bf16(ap1.v, vA0, o10, 0, 0, 0);
        o11 = __builtin_amdgcn_mfma_f32_16x16x32_bf16(ap1.v, vA1, o11, 0, 0, 0);
        ls1 = __builtin_amdgcn_mfma_f32_16x16x32_bf16(ap1.v, ones, ls1, 0, 0, 0);
    }

    #pragma unroll
    for (int r = 0; r < 4; ++r) {
        float i0 = 1.f / ls0[r], i1 = 1.f / ls1[r];
        o00[r] *= i0; o01[r] *= i0;
        o10[r] *= i1; o11[r] *= i1;
    }

    __syncthreads();   // all waves done with k_s; overlay otr on K region
    unsigned short (*otr)[32][40] = (unsigned short(*)[32][40])smem;
    #pragma unroll
    for (int r = 0; r < 4; ++r) {
        otr[wid][g * 4 + r][ln]           = f2bf(o00[r]);
        otr[wid][g * 4 + r][16 + ln]      = f2bf(o01[r]);
        otr[wid][16 + g * 4 + r][ln]      = f2bf(o10[r]);
        otr[wid][16 + g * 4 + r][16 + ln] = f2bf(o11[r]);
    }
    // same-wave region: DS in-order, no barrier.  2 lanes/row x 16 d each.
    const int row = lane >> 1;
    const int ch  = (lane & 1) * 16;
    uint4 st0 = *(uint4*)&otr[wid][row][ch];
    uint4 st1 = *(uint4*)&otr[wid][row][ch + 8];
    unsigned short* dst = &ao16[((size_t)b * NTOK + qb + row) * CDIM + h * HDIM + ch];
    *(uint4*)dst     = st0;
    *(uint4*)&dst[8] = st1;
}

// ---------------------------------------------------------------------------
// Output projection: 64c x 128p per block, wave = 2 c-frags x 4 p-frags.
// XCD-swizzled flat grid 512.
// ---------------------------------------------------------------------------
__global__ __launch_bounds__(256) void outproj_kernel(
    const unsigned short* __restrict__ ao16,  // (b,n,256)
    const unsigned short* __restrict__ wo16,  // (256,256)
    const float* __restrict__ bo,
    float* __restrict__ y)                    // (b,256,n)
{
    const int id   = blockIdx.x;              // 0..511
    const int b    = (id & 7) * 2 + ((id >> 3) & 1);
    const int rest = id >> 4;                 // 0..31
    const int ct   = (rest & 3) * 64;
    const int pt   = (rest >> 2) * 128;
    const int t = threadIdx.x, wid = t >> 6, lane = t & 63;
    const int g = lane >> 4, ln = lane & 15;
    const int cb2 = ct + (wid & 1) * 32;
    const int pb  = pt + (wid >> 1) * 64;
    const unsigned short* ab = ao16 + (size_t)b * NTOK * CDIM;

    f32x4 acc[2][4];
    #pragma unroll
    for (int n = 0; n < 2; ++n)
        #pragma unroll
        for (int m = 0; m < 4; ++m) acc[n][m] = (f32x4){0.f, 0.f, 0.f, 0.f};

    #pragma unroll
    for (int kt = 0; kt < CDIM; kt += 32) {
        bf16x8 aw[2], bx[4];
        #pragma unroll
        for (int n = 0; n < 2; ++n)
            aw[n] = *(const bf16x8*)&wo16[(size_t)(cb2 + n * 16 + ln) * CDIM + kt + g * 8];
        #pragma unroll
        for (int m = 0; m < 4; ++m)
            bx[m] = *(const bf16x8*)&ab[(size_t)(pb + m * 16 + ln) * CDIM + kt + g * 8];
        #pragma unroll
        for (int n = 0; n < 2; ++n)
            #pragma unroll
            for (int m = 0; m < 4; ++m)
                acc[n][m] = __builtin_amdgcn_mfma_f32_16x16x32_bf16(aw[n], bx[m], acc[n][m], 0, 0, 0);
    }
    #pragma unroll
    for (int n = 0; n < 2; ++n)
        #pragma unroll
        for (int r = 0; r < 4; ++r) {
            const int c = cb2 + n * 16 + g * 4 + r;
            const float bias = bo[c];
            #pragma unroll
            for (int m = 0; m < 4; ++m)
                y[((size_t)b * CDIM + c) * NTOK + pb + m * 16 + ln] = acc[n][m][r] + bias;
        }
}

// ---------------------------------------------------------------------------
extern "C" void kernel_launch(void* const* d_in, const int* in_sizes, int n_in,
                              void* d_out, int out_size, void* d_ws, size_t ws_size,
                              hipStream_t stream) {
    const float* x        = (const float*)d_in[0];
    const float* Wq       = (const float*)d_in[1];
    const float* Wk       = (const float*)d_in[2];
    const float* Wv       = (const float*)d_in[3];
    const float* Wo       = (const float*)d_in[4];
    const float* bo       = (const float*)d_in[5];
    const float* rel_bias = (const float*)d_in[6];
    (void)in_sizes; (void)n_in; (void)ws_size; (void)out_size;
    // d_in[7] = rel_idx: unused — bias index computed analytically (j - p + 1056)

    unsigned short* ws16 = (unsigned short*)d_ws;
    unsigned short* xt16 = ws16;                              // 8 MB
    unsigned short* ao16 = ws16 + (size_t)4 * 1024 * 1024;    // 8 MB
    unsigned short* w16  = ws16 + (size_t)8 * 1024 * 1024;    // 512 KB
    float* y = (float*)d_out;

    prep_kernel<<<dim3(16, 4, 17), 256, 0, stream>>>(x, Wq, Wk, Wv, Wo, w16, xt16);
    attn_kernel<<<256, 1024, 0, stream>>>(xt16, w16, rel_bias, ao16);
    outproj_kernel<<<512, 256, 0, stream>>>(ao16, w16 + 3 * 65536, bo, y);
}